// Round 5
// baseline (592.185 us; speedup 1.0000x reference)
//
#include <hip/hip_runtime.h>
#include <hip/hip_bf16.h>

#define N_NODES 10000
#define N_PAD   10016
#define E_EDGES 160000
#define HID 256

typedef __attribute__((ext_vector_type(4))) float f32x4;
typedef __attribute__((ext_vector_type(8))) short bf16x8;
typedef __attribute__((ext_vector_type(8))) unsigned short u16x8;
typedef unsigned short u16;

__device__ __forceinline__ float silu_f(float x) { return x / (1.0f + __expf(-x)); }

__device__ __forceinline__ u16 f2bf(float f) {           // round-to-nearest-even
    unsigned x = __float_as_uint(f);
    unsigned r = x + 0x7FFFu + ((x >> 16) & 1u);
    return (u16)(r >> 16);
}
__device__ __forceinline__ float bf2f(u16 u) {
    return __uint_as_float(((unsigned)u) << 16);
}
__device__ __forceinline__ f32x4 mfma16(bf16x8 a, bf16x8 b, f32x4 c) {
    return __builtin_amdgcn_mfma_f32_16x16x32_bf16(a, b, c, 0, 0, 0);
}
// swizzled byte offset into a [rows][256] u16 activation tile (stride 512B)
__device__ __forceinline__ int actb(int row, int elem) {
    return (row * 512 + elem * 2) ^ ((row & 7) << 4);
}

// ---------------------------------------------------------------------------
// prep: weight transposes -> bf16 [n][k] layouts
// ---------------------------------------------------------------------------
__global__ __launch_bounds__(256) void prep_weights(
    const float* __restrict__ eW1, const float* __restrict__ eW2,
    const float* __restrict__ cW1, const float* __restrict__ nW1,
    const float* __restrict__ nW2,
    u16* __restrict__ Wt3, u16* __restrict__ e1pt, u16* __restrict__ e2t,
    u16* __restrict__ c1t, u16* __restrict__ n1t, u16* __restrict__ n2t)
{
    const int y = blockIdx.y;
    const float* src; u16* dst; int Ks, Kd;
    switch (y) {
        case 0: src = eW1;                dst = Wt3;                Ks = 512; Kd = 512; break;
        case 1: src = eW1 + 512 * 256;    dst = Wt3 + 256 * 512;    Ks = 512; Kd = 512; break;
        case 2: src = nW1;                dst = Wt3 + 2 * 256 * 512; Ks = 512; Kd = 512; break;
        case 3: src = eW1 + 1024 * 256;   dst = e1pt;               Ks = 52;  Kd = 64;  break; // attr rows + radial row (1075)
        case 4: src = eW2;                dst = e2t;                Ks = 256; Kd = 256; break;
        case 5: src = cW1;                dst = c1t;                Ks = 256; Kd = 256; break;
        case 6: src = nW1 + 512 * 256;    dst = n1t;                Ks = 256; Kd = 256; break;
        default: src = nW2;               dst = n2t;                Ks = 256; Kd = 256; break;
    }
    int idx = blockIdx.x * 256 + threadIdx.x;
    if (idx < 256 * Kd) {
        int n = idx / Kd, k = idx - n * Kd;
        dst[idx] = (k < Ks) ? f2bf(src[(size_t)k * 256 + n]) : (u16)0;
    }
}

// h (f32) -> h_bf (bf16), zero-padded rows to N_PAD
__global__ __launch_bounds__(256) void conv_h(const float* __restrict__ h, u16* __restrict__ hb)
{
    size_t base = ((size_t)blockIdx.x * 256 + threadIdx.x) * 8;
    int row = (int)(base >> 9);
    u16x8 o;
    if (row < N_NODES) {
        const float4 f0 = *(const float4*)&h[base];
        const float4 f1 = *(const float4*)&h[base + 4];
        o[0] = f2bf(f0.x); o[1] = f2bf(f0.y); o[2] = f2bf(f0.z); o[3] = f2bf(f0.w);
        o[4] = f2bf(f1.x); o[5] = f2bf(f1.y); o[6] = f2bf(f1.z); o[7] = f2bf(f1.w);
    } else {
        o = (u16x8)0;
    }
    *(u16x8*)&hb[base] = o;
}

// ---------------------------------------------------------------------------
// counting sort of edges by destination row: hist -> scan -> scatter
// ---------------------------------------------------------------------------
__global__ __launch_bounds__(256) void hist_kernel(const int* __restrict__ row,
                                                   int* __restrict__ hist)
{
    int e = blockIdx.x * 256 + threadIdx.x;
    if (e < E_EDGES) atomicAdd(&hist[row[e]], 1);
}

#define SCAN_PER 40   // 256*40 >= N_PAD
__global__ __launch_bounds__(256) void scan_kernel(const int* __restrict__ hist,
                                                   int* __restrict__ rowptr)
{
    __shared__ int a[256];
    const int t = threadIdx.x;
    const int base = t * SCAN_PER;
    int s = 0;
    for (int i = 0; i < SCAN_PER; ++i) {
        int b = base + i;
        if (b < N_PAD) s += hist[b];
    }
    a[t] = s;
    __syncthreads();
    for (int off = 1; off < 256; off <<= 1) {
        int v = (t >= off) ? a[t - off] : 0;
        __syncthreads();
        a[t] += v;
        __syncthreads();
    }
    int run = a[t] - s;      // exclusive base for this thread's span
    for (int i = 0; i < SCAN_PER; ++i) {
        int b = base + i;
        if (b < N_PAD) { rowptr[b] = run; run += hist[b]; }
    }
    if (t == 255) rowptr[N_PAD] = a[255];
}

__global__ __launch_bounds__(256) void scatter_kernel(const int* __restrict__ row,
                                                      const int* __restrict__ rowptr,
                                                      int* __restrict__ cnt,
                                                      int* __restrict__ eorder)
{
    int e = blockIdx.x * 256 + threadIdx.x;
    if (e < E_EDGES) {
        int r = row[e];
        int p = rowptr[r] + atomicAdd(&cnt[r], 1);
        eorder[p] = e;
    }
}

// ---------------------------------------------------------------------------
// Xb[n][0:256]=h@eW1[:512], [256:512]=h@eW1[512:1024], [512:768]=h@nW1[:512] (bf16)
// ---------------------------------------------------------------------------
__global__ __launch_bounds__(256) void precompute_X(
    const u16* __restrict__ hb, const u16* __restrict__ Wt3, u16* __restrict__ Xb)
{
    const int n0b = blockIdx.x * 32;
    const int which = blockIdx.y;
    const int j = threadIdx.x, wv = j >> 6, lane = j & 63;
    const int ml = lane & 15, g = lane >> 4;
    const int n0 = wv * 64;
    const u16* W = Wt3 + (size_t)which * 256 * 512;

    f32x4 acc[2][4];
    const f32x4 z = {0.f, 0.f, 0.f, 0.f};
#pragma unroll
    for (int mt = 0; mt < 2; ++mt)
#pragma unroll
        for (int nt = 0; nt < 4; ++nt) acc[mt][nt] = z;

    for (int kc = 0; kc < 16; ++kc) {
        bf16x8 a0 = *(const bf16x8*)&hb[(size_t)(n0b + ml) * 512 + kc * 32 + g * 8];
        bf16x8 a1 = *(const bf16x8*)&hb[(size_t)(n0b + 16 + ml) * 512 + kc * 32 + g * 8];
#pragma unroll
        for (int nt = 0; nt < 4; ++nt) {
            bf16x8 b = *(const bf16x8*)&W[(size_t)(n0 + nt * 16 + ml) * 512 + kc * 32 + g * 8];
            acc[0][nt] = mfma16(a0, b, acc[0][nt]);
            acc[1][nt] = mfma16(a1, b, acc[1][nt]);
        }
    }
#pragma unroll
    for (int mt = 0; mt < 2; ++mt)
#pragma unroll
        for (int nt = 0; nt < 4; ++nt) {
            int col = n0 + nt * 16 + ml;
#pragma unroll
            for (int i = 0; i < 4; ++i) {
                int row = n0b + mt * 16 + g * 4 + i;
                Xb[(size_t)row * 768 + which * 256 + col] = f2bf(acc[mt][nt][i]);
            }
        }
}

// ---------------------------------------------------------------------------
// edge kernel v2: WAVE-INDEPENDENT. Each wave owns 32 sorted edges end-to-end
// (acc = 2 m-tiles x 16 n-tiles = full 256 cols), wave-private 16KB LDS tile
// reused xsum->act1->act2 in place. ZERO __syncthreads.
// ---------------------------------------------------------------------------
__global__ __launch_bounds__(256, 2) void edge_kernel(
    const u16* __restrict__ Xb, const float* __restrict__ pos,
    const int* __restrict__ eidx, const float* __restrict__ eattr,
    const int* __restrict__ eorder,
    const u16* __restrict__ e1pt, const float* __restrict__ eb1,
    const u16* __restrict__ e2t, const float* __restrict__ eb2,
    const u16* __restrict__ c1t, const float* __restrict__ cb1,
    const float* __restrict__ cW2,
    float* __restrict__ agg_node, float* __restrict__ agg_coord)
{
    __shared__ u16 buf[4][32 * 256];          // 64 KB: 16KB wave-private tiles
    __shared__ int   ri_s[4][32], ci_s[4][32], es_s[4][32];
    __shared__ float rad_s[4][32], dif_s[4][32][3];

    const int j = threadIdx.x, w = j >> 6, lane = j & 63;
    const int ml = lane & 15, g = lane >> 4;
    const f32x4 z = {0.f, 0.f, 0.f, 0.f};

    // bijective XCD-chunked swizzle (m204): consecutive sorted-edge blocks
    // stay on one XCD's L2 (Xr row reuse).
    const int nwg = gridDim.x;
    const int qq = nwg >> 3, r8 = nwg & 7;
    const int xcd = blockIdx.x & 7, sub = blockIdx.x >> 3;
    const int wg = (xcd < r8 ? xcd * (qq + 1) : r8 * (qq + 1) + (xcd - r8) * qq) + sub;

    const int e0 = wg * 128 + w * 32;
    u16* bufw = buf[w];

    if (lane < 32) {
        int e = eorder[e0 + lane];
        es_s[w][lane] = e;
        int r = eidx[e], c = eidx[E_EDGES + e];
        ri_s[w][lane] = r; ci_s[w][lane] = c;
        float dx = pos[r * 3 + 0] - pos[c * 3 + 0];
        float dy = pos[r * 3 + 1] - pos[c * 3 + 1];
        float dz = pos[r * 3 + 2] - pos[c * 3 + 2];
        dif_s[w][lane][0] = dx; dif_s[w][lane][1] = dy; dif_s[w][lane][2] = dz;
        rad_s[w][lane] = sqrtf(dx * dx + dy * dy + dz * dz) + 1e-8f;
    }
    asm volatile("s_waitcnt lgkmcnt(0)" ::: "memory");
    __builtin_amdgcn_sched_barrier(0);

    // ---- cooperative (within-wave) gather: buf = Xr[ri] + Xc[ci] (bf16)
#pragma unroll
    for (int t = 0; t < 16; ++t) {
        int li = t * 64 + lane;
        int e = li >> 5, c = li & 31;
        const u16x8 xr = *(const u16x8*)&Xb[(size_t)ri_s[w][e] * 768 + c * 8];
        const u16x8 xc = *(const u16x8*)&Xb[(size_t)ci_s[w][e] * 768 + 256 + c * 8];
        u16x8 o;
#pragma unroll
        for (int k = 0; k < 8; ++k) o[k] = f2bf(bf2f(xr[k]) + bf2f(xc[k]));
        *(u16x8*)((char*)bufw + ((e * 512 + c * 16) ^ ((e & 7) << 4))) = o;
    }

    // ---- attr/radial A-fragments built directly in registers
    bf16x8 af[2][2];
#pragma unroll
    for (int mt = 0; mt < 2; ++mt) {
        int row = mt * 16 + ml;
        const float* ap = eattr + (size_t)es_s[w][row] * 51;
        float rd = rad_s[w][row];
        int k0 = g * 8;
        bf16x8 f0, f1;
#pragma unroll
        for (int t = 0; t < 8; ++t) f0[t] = (short)f2bf(ap[k0 + t]);
        if (g < 2) {
            int k1 = 32 + g * 8;
#pragma unroll
            for (int t = 0; t < 8; ++t) f1[t] = (short)f2bf(ap[k1 + t]);
        } else if (g == 2) {
            f1[0] = (short)f2bf(ap[48]); f1[1] = (short)f2bf(ap[49]);
            f1[2] = (short)f2bf(ap[50]); f1[3] = (short)f2bf(rd);
            f1[4] = 0; f1[5] = 0; f1[6] = 0; f1[7] = 0;
        } else {
            f1 = (bf16x8)0;
        }
        af[mt][0] = f0; af[mt][1] = f1;
    }
    asm volatile("s_waitcnt lgkmcnt(0)" ::: "memory");
    __builtin_amdgcn_sched_barrier(0);

    f32x4 acc[2][16];
#pragma unroll
    for (int mt = 0; mt < 2; ++mt)
#pragma unroll
        for (int nt = 0; nt < 16; ++nt) acc[mt][nt] = z;

    // ---- stage 1: attr MFMA (K=64)
#pragma unroll
    for (int kc = 0; kc < 2; ++kc)
#pragma unroll
        for (int nt = 0; nt < 16; ++nt) {
            bf16x8 b = *(const bf16x8*)&e1pt[(size_t)(nt * 16 + ml) * 64 + kc * 32 + g * 8];
            acc[0][nt] = mfma16(af[0][kc], b, acc[0][nt]);
            acc[1][nt] = mfma16(af[1][kc], b, acc[1][nt]);
        }
    // epilogue: + bias + xsum (in-place read/write), silu -> act1
#pragma unroll
    for (int nt = 0; nt < 16; ++nt) {
        int col = nt * 16 + ml;
        float b1 = eb1[col];
#pragma unroll
        for (int mt = 0; mt < 2; ++mt)
#pragma unroll
            for (int i = 0; i < 4; ++i) {
                int row = mt * 16 + g * 4 + i;
                int off = actb(row, col) >> 1;
                float v = acc[mt][nt][i] + b1 + bf2f(bufw[off]);
                bufw[off] = f2bf(silu_f(v));
            }
    }
    asm volatile("s_waitcnt lgkmcnt(0)" ::: "memory");
    __builtin_amdgcn_sched_barrier(0);

    // ---- stage 2: e = silu(act1 @ eW2 + eb2) -> act2 (in place)
#pragma unroll
    for (int mt = 0; mt < 2; ++mt)
#pragma unroll
        for (int nt = 0; nt < 16; ++nt) acc[mt][nt] = z;
#pragma unroll
    for (int kc = 0; kc < 8; ++kc) {
        bf16x8 a0 = *(const bf16x8*)((const char*)bufw + actb(ml, kc * 32 + g * 8));
        bf16x8 a1 = *(const bf16x8*)((const char*)bufw + actb(16 + ml, kc * 32 + g * 8));
#pragma unroll
        for (int nt = 0; nt < 16; ++nt) {
            bf16x8 b = *(const bf16x8*)&e2t[(size_t)(nt * 16 + ml) * 256 + kc * 32 + g * 8];
            acc[0][nt] = mfma16(a0, b, acc[0][nt]);
            acc[1][nt] = mfma16(a1, b, acc[1][nt]);
        }
    }
#pragma unroll
    for (int nt = 0; nt < 16; ++nt) {
        int col = nt * 16 + ml;
        float b2 = eb2[col];
#pragma unroll
        for (int mt = 0; mt < 2; ++mt)
#pragma unroll
            for (int i = 0; i < 4; ++i) {
                int row = mt * 16 + g * 4 + i;
                bufw[actb(row, col) >> 1] = f2bf(silu_f(acc[mt][nt][i] + b2));
            }
    }
    asm volatile("s_waitcnt lgkmcnt(0)" ::: "memory");
    __builtin_amdgcn_sched_barrier(0);

    // ---- run-length agg_node: lane owns 4 columns, rows sorted -> one
    // atomic per distinct destination row per column.
    {
        int cur = ri_s[w][0];
        float s0 = bf2f(bufw[actb(0, lane) >> 1]);
        float s1 = bf2f(bufw[actb(0, lane + 64) >> 1]);
        float s2 = bf2f(bufw[actb(0, lane + 128) >> 1]);
        float s3 = bf2f(bufw[actb(0, lane + 192) >> 1]);
        for (int m = 1; m < 32; ++m) {
            int r = ri_s[w][m];
            float v0 = bf2f(bufw[actb(m, lane) >> 1]);
            float v1 = bf2f(bufw[actb(m, lane + 64) >> 1]);
            float v2 = bf2f(bufw[actb(m, lane + 128) >> 1]);
            float v3 = bf2f(bufw[actb(m, lane + 192) >> 1]);
            if (r != cur) {
                atomicAdd(&agg_node[(size_t)cur * 256 + lane], s0);
                atomicAdd(&agg_node[(size_t)cur * 256 + lane + 64], s1);
                atomicAdd(&agg_node[(size_t)cur * 256 + lane + 128], s2);
                atomicAdd(&agg_node[(size_t)cur * 256 + lane + 192], s3);
                s0 = 0.f; s1 = 0.f; s2 = 0.f; s3 = 0.f; cur = r;
            }
            s0 += v0; s1 += v1; s2 += v2; s3 += v3;
        }
        atomicAdd(&agg_node[(size_t)cur * 256 + lane], s0);
        atomicAdd(&agg_node[(size_t)cur * 256 + lane + 64], s1);
        atomicAdd(&agg_node[(size_t)cur * 256 + lane + 128], s2);
        atomicAdd(&agg_node[(size_t)cur * 256 + lane + 192], s3);
    }

    // ---- stage 3: u = clip((silu(act2 @ cW1 + cb1)) . cW2), coord atomics
#pragma unroll
    for (int mt = 0; mt < 2; ++mt)
#pragma unroll
        for (int nt = 0; nt < 16; ++nt) acc[mt][nt] = z;
#pragma unroll
    for (int kc = 0; kc < 8; ++kc) {
        bf16x8 a0 = *(const bf16x8*)((const char*)bufw + actb(ml, kc * 32 + g * 8));
        bf16x8 a1 = *(const bf16x8*)((const char*)bufw + actb(16 + ml, kc * 32 + g * 8));
#pragma unroll
        for (int nt = 0; nt < 16; ++nt) {
            bf16x8 b = *(const bf16x8*)&c1t[(size_t)(nt * 16 + ml) * 256 + kc * 32 + g * 8];
            acc[0][nt] = mfma16(a0, b, acc[0][nt]);
            acc[1][nt] = mfma16(a1, b, acc[1][nt]);
        }
    }
    float p[2][4] = {{0.f, 0.f, 0.f, 0.f}, {0.f, 0.f, 0.f, 0.f}};
#pragma unroll
    for (int nt = 0; nt < 16; ++nt) {
        int col = nt * 16 + ml;
        float b3 = cb1[col];
        float w2 = cW2[col];
#pragma unroll
        for (int mt = 0; mt < 2; ++mt)
#pragma unroll
            for (int i = 0; i < 4; ++i)
                p[mt][i] += silu_f(acc[mt][nt][i] + b3) * w2;
    }
#pragma unroll
    for (int mt = 0; mt < 2; ++mt)
#pragma unroll
        for (int i = 0; i < 4; ++i) {
            float v = p[mt][i];
            v += __shfl_xor(v, 1);
            v += __shfl_xor(v, 2);
            v += __shfl_xor(v, 4);
            v += __shfl_xor(v, 8);
            p[mt][i] = v;
        }
    if (ml == 0) {
#pragma unroll
        for (int mt = 0; mt < 2; ++mt)
#pragma unroll
            for (int i = 0; i < 4; ++i) {
                int row = mt * 16 + g * 4 + i;
                float u = fminf(fmaxf(p[mt][i], -1.f), 1.f);
                int rr = ri_s[w][row];
                atomicAdd(&agg_coord[(size_t)rr * 3 + 0], u * dif_s[w][row][0]);
                atomicAdd(&agg_coord[(size_t)rr * 3 + 1], u * dif_s[w][row][1]);
                atomicAdd(&agg_coord[(size_t)rr * 3 + 2], u * dif_s[w][row][2]);
            }
    }
}

// ---------------------------------------------------------------------------
// node kernel: h_new = silu([h,agg] @ nW1 + nb1) @ nW2 + nb2 ; pos update
// ---------------------------------------------------------------------------
__global__ __launch_bounds__(256) void node_kernel(
    const u16* __restrict__ Xb, const float* __restrict__ agg_node,
    const float* __restrict__ agg_coord, const float* __restrict__ pos,
    const u16* __restrict__ n1t, const float* __restrict__ nb1,
    const u16* __restrict__ n2t, const float* __restrict__ nb2,
    float* __restrict__ out)
{
    __shared__ u16 act1[32 * 256];
    __shared__ u16 act2[32 * 256];
    const int n0b = blockIdx.x * 32;
    const int j = threadIdx.x, wv = j >> 6, lane = j & 63;
    const int ml = lane & 15, g = lane >> 4;
    const int n0 = wv * 64;
    const f32x4 z = {0.f, 0.f, 0.f, 0.f};

    for (int li = j; li < 32 * 256; li += 256) {
        int r = li >> 8, c = li & 255;
        act1[actb(r, c) >> 1] = f2bf(agg_node[(size_t)(n0b + r) * 256 + c]);
    }
    __syncthreads();

    f32x4 acc[2][4];
#pragma unroll
    for (int mt = 0; mt < 2; ++mt)
#pragma unroll
        for (int nt = 0; nt < 4; ++nt) acc[mt][nt] = z;
    for (int kc = 0; kc < 8; ++kc) {
        bf16x8 a0 = *(const bf16x8*)((const char*)act1 + actb(ml, kc * 32 + g * 8));
        bf16x8 a1 = *(const bf16x8*)((const char*)act1 + actb(16 + ml, kc * 32 + g * 8));
#pragma unroll
        for (int nt = 0; nt < 4; ++nt) {
            bf16x8 b = *(const bf16x8*)&n1t[(size_t)(n0 + nt * 16 + ml) * 256 + kc * 32 + g * 8];
            acc[0][nt] = mfma16(a0, b, acc[0][nt]);
            acc[1][nt] = mfma16(a1, b, acc[1][nt]);
        }
    }
#pragma unroll
    for (int mt = 0; mt < 2; ++mt)
#pragma unroll
        for (int nt = 0; nt < 4; ++nt) {
            int col = n0 + nt * 16 + ml;
            float b1 = nb1[col];
#pragma unroll
            for (int i = 0; i < 4; ++i) {
                int m = mt * 16 + g * 4 + i;
                float v = acc[mt][nt][i] + b1 + bf2f(Xb[(size_t)(n0b + m) * 768 + 512 + col]);
                act2[actb(m, col) >> 1] = f2bf(silu_f(v));
            }
        }
    __syncthreads();
#pragma unroll
    for (int mt = 0; mt < 2; ++mt)
#pragma unroll
        for (int nt = 0; nt < 4; ++nt) acc[mt][nt] = z;
    for (int kc = 0; kc < 8; ++kc) {
        bf16x8 a0 = *(const bf16x8*)((const char*)act2 + actb(ml, kc * 32 + g * 8));
        bf16x8 a1 = *(const bf16x8*)((const char*)act2 + actb(16 + ml, kc * 32 + g * 8));
#pragma unroll
        for (int nt = 0; nt < 4; ++nt) {
            bf16x8 b = *(const bf16x8*)&n2t[(size_t)(n0 + nt * 16 + ml) * 256 + kc * 32 + g * 8];
            acc[0][nt] = mfma16(a0, b, acc[0][nt]);
            acc[1][nt] = mfma16(a1, b, acc[1][nt]);
        }
    }
#pragma unroll
    for (int mt = 0; mt < 2; ++mt)
#pragma unroll
        for (int nt = 0; nt < 4; ++nt) {
            int col = n0 + nt * 16 + ml;
            float b2 = nb2[col];
#pragma unroll
            for (int i = 0; i < 4; ++i) {
                int row = n0b + mt * 16 + g * 4 + i;
                if (row < N_NODES)
                    out[(size_t)row * 256 + col] = acc[mt][nt][i] + b2;
            }
        }
    if (j < 96) {
        int idx = n0b * 3 + j;
        if (idx < N_NODES * 3)
            out[(size_t)N_NODES * 256 + idx] = pos[idx] + agg_coord[idx];
    }
}

// ---------------------------------------------------------------------------
extern "C" void kernel_launch(void* const* d_in, const int* in_sizes, int n_in,
                              void* d_out, int out_size, void* d_ws, size_t ws_size,
                              hipStream_t stream)
{
    (void)in_sizes; (void)n_in; (void)out_size; (void)ws_size;
    const float* h     = (const float*)d_in[0];
    const int*   eidx  = (const int*)d_in[1];
    const float* eattr = (const float*)d_in[2];
    const float* pos   = (const float*)d_in[3];
    const float* eW1   = (const float*)d_in[4];
    const float* eb1   = (const float*)d_in[5];
    const float* eW2   = (const float*)d_in[6];
    const float* eb2   = (const float*)d_in[7];
    const float* cW1   = (const float*)d_in[8];
    const float* cb1   = (const float*)d_in[9];
    const float* cW2   = (const float*)d_in[10];
    const float* nW1   = (const float*)d_in[11];
    const float* nb1   = (const float*)d_in[12];
    const float* nW2   = (const float*)d_in[13];
    const float* nb2   = (const float*)d_in[14];
    float* out = (float*)d_out;

    u16* Xb   = (u16*)d_ws;                                  // N_PAD*768 bf16
    u16* hb   = Xb + (size_t)N_PAD * 768;                    // N_PAD*512
    u16* Wt3  = hb + (size_t)N_PAD * 512;                    // 3*256*512
    u16* e1pt = Wt3 + 3 * 256 * 512;                         // 256*64
    u16* e2t  = e1pt + 256 * 64;                             // 256*256
    u16* c1t  = e2t + 256 * 256;
    u16* n1t  = c1t + 256 * 256;
    u16* n2t  = n1t + 256 * 256;
    float* agg_node  = (float*)(n2t + 256 * 256);            // N_PAD*256 f32
    float* agg_coord = agg_node + (size_t)N_PAD * 256;       // N_PAD*3  f32
    int* hist   = (int*)(agg_coord + (size_t)N_PAD * 3);     // N_PAD
    int* cnt    = hist + N_PAD;                              // N_PAD
    int* rowptr = cnt + N_PAD;                               // N_PAD+1
    int* eorder = rowptr + N_PAD + 1;                        // E

    hipMemsetAsync(agg_node, 0, (size_t)N_PAD * 259 * sizeof(float), stream);
    hipMemsetAsync(hist, 0, (size_t)2 * N_PAD * sizeof(int), stream);

    prep_weights<<<dim3(512, 8), 256, 0, stream>>>(eW1, eW2, cW1, nW1, nW2,
                                                   Wt3, e1pt, e2t, c1t, n1t, n2t);
    conv_h<<<(N_PAD * 512 / 8) / 256, 256, 0, stream>>>(h, hb);

    hist_kernel<<<(E_EDGES + 255) / 256, 256, 0, stream>>>(eidx, hist);
    scan_kernel<<<1, 256, 0, stream>>>(hist, rowptr);
    scatter_kernel<<<(E_EDGES + 255) / 256, 256, 0, stream>>>(eidx, rowptr, cnt, eorder);

    precompute_X<<<dim3(N_PAD / 32, 3), 256, 0, stream>>>(hb, Wt3, Xb);

    edge_kernel<<<E_EDGES / 128, 256, 0, stream>>>(
        Xb, pos, eidx, eattr, eorder, e1pt, eb1, e2t, eb2, c1t, cb1, cW2,
        agg_node, agg_coord);

    node_kernel<<<N_PAD / 32, 256, 0, stream>>>(
        Xb, agg_node, agg_coord, pos, n1t, nb1, n2t, nb2, out);
}

// Round 6
// 476.718 us; speedup vs baseline: 1.2422x; 1.2422x over previous
//
#include <hip/hip_runtime.h>
#include <hip/hip_bf16.h>

#define N_NODES 10000
#define N_PAD   10016
#define E_EDGES 160000
#define EB 64     // edges per block (edge kernel v3)
#define HID 256

typedef __attribute__((ext_vector_type(4))) float f32x4;
typedef __attribute__((ext_vector_type(8))) short bf16x8;
typedef __attribute__((ext_vector_type(8))) unsigned short u16x8;
typedef unsigned short u16;

__device__ __forceinline__ float silu_f(float x) { return x / (1.0f + __expf(-x)); }

__device__ __forceinline__ u16 f2bf(float f) {           // round-to-nearest-even
    unsigned x = __float_as_uint(f);
    unsigned r = x + 0x7FFFu + ((x >> 16) & 1u);
    return (u16)(r >> 16);
}
__device__ __forceinline__ float bf2f(u16 u) {
    return __uint_as_float(((unsigned)u) << 16);
}
__device__ __forceinline__ f32x4 mfma16(bf16x8 a, bf16x8 b, f32x4 c) {
    return __builtin_amdgcn_mfma_f32_16x16x32_bf16(a, b, c, 0, 0, 0);
}
// swizzled byte offset into a [rows][256] u16 activation tile (stride 512B)
__device__ __forceinline__ int actb(int row, int elem) {
    return (row * 512 + elem * 2) ^ ((row & 7) << 4);
}

// ---------------------------------------------------------------------------
// prep: weight transposes -> bf16 [n][k] layouts
// ---------------------------------------------------------------------------
__global__ __launch_bounds__(256) void prep_weights(
    const float* __restrict__ eW1, const float* __restrict__ eW2,
    const float* __restrict__ cW1, const float* __restrict__ nW1,
    const float* __restrict__ nW2,
    u16* __restrict__ Wt3, u16* __restrict__ e1pt, u16* __restrict__ e2t,
    u16* __restrict__ c1t, u16* __restrict__ n1t, u16* __restrict__ n2t)
{
    const int y = blockIdx.y;
    const float* src; u16* dst; int Ks, Kd;
    switch (y) {
        case 0: src = eW1;                dst = Wt3;                Ks = 512; Kd = 512; break;
        case 1: src = eW1 + 512 * 256;    dst = Wt3 + 256 * 512;    Ks = 512; Kd = 512; break;
        case 2: src = nW1;                dst = Wt3 + 2 * 256 * 512; Ks = 512; Kd = 512; break;
        case 3: src = eW1 + 1024 * 256;   dst = e1pt;               Ks = 52;  Kd = 64;  break; // attr rows + radial row (1075)
        case 4: src = eW2;                dst = e2t;                Ks = 256; Kd = 256; break;
        case 5: src = cW1;                dst = c1t;                Ks = 256; Kd = 256; break;
        case 6: src = nW1 + 512 * 256;    dst = n1t;                Ks = 256; Kd = 256; break;
        default: src = nW2;               dst = n2t;                Ks = 256; Kd = 256; break;
    }
    int idx = blockIdx.x * 256 + threadIdx.x;
    if (idx < 256 * Kd) {
        int n = idx / Kd, k = idx - n * Kd;
        dst[idx] = (k < Ks) ? f2bf(src[(size_t)k * 256 + n]) : (u16)0;
    }
}

// h (f32) -> h_bf (bf16), zero-padded rows to N_PAD
__global__ __launch_bounds__(256) void conv_h(const float* __restrict__ h, u16* __restrict__ hb)
{
    size_t base = ((size_t)blockIdx.x * 256 + threadIdx.x) * 8;
    int row = (int)(base >> 9);
    u16x8 o;
    if (row < N_NODES) {
        const float4 f0 = *(const float4*)&h[base];
        const float4 f1 = *(const float4*)&h[base + 4];
        o[0] = f2bf(f0.x); o[1] = f2bf(f0.y); o[2] = f2bf(f0.z); o[3] = f2bf(f0.w);
        o[4] = f2bf(f1.x); o[5] = f2bf(f1.y); o[6] = f2bf(f1.z); o[7] = f2bf(f1.w);
    } else {
        o = (u16x8)0;
    }
    *(u16x8*)&hb[base] = o;
}

// ---------------------------------------------------------------------------
// counting sort of edges by destination row: hist -> scan -> scatter
// ---------------------------------------------------------------------------
__global__ __launch_bounds__(256) void hist_kernel(const int* __restrict__ row,
                                                   int* __restrict__ hist)
{
    int e = blockIdx.x * 256 + threadIdx.x;
    if (e < E_EDGES) atomicAdd(&hist[row[e]], 1);
}

#define SCAN_PER 40   // 256*40 >= N_PAD
__global__ __launch_bounds__(256) void scan_kernel(const int* __restrict__ hist,
                                                   int* __restrict__ rowptr)
{
    __shared__ int a[256];
    const int t = threadIdx.x;
    const int base = t * SCAN_PER;
    int s = 0;
    for (int i = 0; i < SCAN_PER; ++i) {
        int b = base + i;
        if (b < N_PAD) s += hist[b];
    }
    a[t] = s;
    __syncthreads();
    for (int off = 1; off < 256; off <<= 1) {
        int v = (t >= off) ? a[t - off] : 0;
        __syncthreads();
        a[t] += v;
        __syncthreads();
    }
    int run = a[t] - s;      // exclusive base for this thread's span
    for (int i = 0; i < SCAN_PER; ++i) {
        int b = base + i;
        if (b < N_PAD) { rowptr[b] = run; run += hist[b]; }
    }
    if (t == 255) rowptr[N_PAD] = a[255];
}

__global__ __launch_bounds__(256) void scatter_kernel(const int* __restrict__ row,
                                                      const int* __restrict__ rowptr,
                                                      int* __restrict__ cnt,
                                                      int* __restrict__ eorder)
{
    int e = blockIdx.x * 256 + threadIdx.x;
    if (e < E_EDGES) {
        int r = row[e];
        int p = rowptr[r] + atomicAdd(&cnt[r], 1);
        eorder[p] = e;
    }
}

// ---------------------------------------------------------------------------
// Xb[n][0:256]=h@eW1[:512], [256:512]=h@eW1[512:1024], [512:768]=h@nW1[:512] (bf16)
// ---------------------------------------------------------------------------
__global__ __launch_bounds__(256) void precompute_X(
    const u16* __restrict__ hb, const u16* __restrict__ Wt3, u16* __restrict__ Xb)
{
    const int n0b = blockIdx.x * 32;
    const int which = blockIdx.y;
    const int j = threadIdx.x, wv = j >> 6, lane = j & 63;
    const int ml = lane & 15, g = lane >> 4;
    const int n0 = wv * 64;
    const u16* W = Wt3 + (size_t)which * 256 * 512;

    f32x4 acc[2][4];
    const f32x4 z = {0.f, 0.f, 0.f, 0.f};
#pragma unroll
    for (int mt = 0; mt < 2; ++mt)
#pragma unroll
        for (int nt = 0; nt < 4; ++nt) acc[mt][nt] = z;

    for (int kc = 0; kc < 16; ++kc) {
        bf16x8 a0 = *(const bf16x8*)&hb[(size_t)(n0b + ml) * 512 + kc * 32 + g * 8];
        bf16x8 a1 = *(const bf16x8*)&hb[(size_t)(n0b + 16 + ml) * 512 + kc * 32 + g * 8];
#pragma unroll
        for (int nt = 0; nt < 4; ++nt) {
            bf16x8 b = *(const bf16x8*)&W[(size_t)(n0 + nt * 16 + ml) * 512 + kc * 32 + g * 8];
            acc[0][nt] = mfma16(a0, b, acc[0][nt]);
            acc[1][nt] = mfma16(a1, b, acc[1][nt]);
        }
    }
#pragma unroll
    for (int mt = 0; mt < 2; ++mt)
#pragma unroll
        for (int nt = 0; nt < 4; ++nt) {
            int col = n0 + nt * 16 + ml;
#pragma unroll
            for (int i = 0; i < 4; ++i) {
                int row = n0b + mt * 16 + g * 4 + i;
                Xb[(size_t)row * 768 + which * 256 + col] = f2bf(acc[mt][nt][i]);
            }
        }
}

// ---------------------------------------------------------------------------
// edge kernel v3: 64 sorted edges/block, 512 threads (8 waves = 2 row-halves
// x 4 col-groups). Single LDS tile reused xsum->act1->act2 in place.
// Per-wave acc = 2x4 f32x4 (32 VGPR, no spill).
// ---------------------------------------------------------------------------
__global__ __launch_bounds__(512, 2) void edge_kernel(
    const u16* __restrict__ Xb, const float* __restrict__ pos,
    const int* __restrict__ eidx, const float* __restrict__ eattr,
    const int* __restrict__ eorder,
    const u16* __restrict__ e1pt, const float* __restrict__ eb1,
    const u16* __restrict__ e2t, const float* __restrict__ eb2,
    const u16* __restrict__ c1t, const float* __restrict__ cb1,
    const float* __restrict__ cW2,
    float* __restrict__ agg_node, float* __restrict__ agg_coord)
{
    __shared__ u16 attr[EB * 64];     // 8 KB, swizzled rows (stride 128B)
    __shared__ u16 bufA[EB * 256];    // 32 KB, xsum -> act1 -> act2 in place
    __shared__ int ri_s[EB], ci_s[EB], es_s[EB];
    __shared__ float rad_s[EB], dif_s[EB][3];
    __shared__ float red[EB * 4];

    const int j = threadIdx.x, w = j >> 6, lane = j & 63;
    const int ml = lane & 15, g = lane >> 4;
    const int rbase = (w >> 2) * 32;  // row half: rows rbase..rbase+31
    const int cg = w & 3;             // col group
    const int n0 = cg * 64;           // cols n0..n0+63
    const f32x4 z = {0.f, 0.f, 0.f, 0.f};

    // bijective XCD-chunked swizzle: consecutive sorted-edge blocks share L2
    const int nwg = gridDim.x;
    const int qq = nwg >> 3, r8 = nwg & 7;
    const int xcd = blockIdx.x & 7, sub = blockIdx.x >> 3;
    const int wg = (xcd < r8 ? xcd * (qq + 1) : r8 * (qq + 1) + (xcd - r8) * qq) + sub;
    const int e0 = wg * EB;

    if (j < EB) {
        int e = eorder[e0 + j];
        es_s[j] = e;
        int r = eidx[e], c = eidx[E_EDGES + e];
        ri_s[j] = r; ci_s[j] = c;
        float dx = pos[r * 3 + 0] - pos[c * 3 + 0];
        float dy = pos[r * 3 + 1] - pos[c * 3 + 1];
        float dz = pos[r * 3 + 2] - pos[c * 3 + 2];
        dif_s[j][0] = dx; dif_s[j][1] = dy; dif_s[j][2] = dz;
        rad_s[j] = sqrtf(dx * dx + dy * dy + dz * dz) + 1e-8f;
    }
    __syncthreads();

    // ---- cooperative gather: bufA[e][:] = Xr[ri[e]] + Xc[ci[e]] (bf16)
#pragma unroll
    for (int t = 0; t < 4; ++t) {
        int li = t * 512 + j;           // (edge, 16B-chunk)
        int e = li >> 5, c = li & 31;
        const u16x8 xr = *(const u16x8*)&Xb[(size_t)ri_s[e] * 768 + c * 8];
        const u16x8 xc = *(const u16x8*)&Xb[(size_t)ci_s[e] * 768 + 256 + c * 8];
        u16x8 o;
#pragma unroll
        for (int k = 0; k < 8; ++k) o[k] = f2bf(bf2f(xr[k]) + bf2f(xc[k]));
        *(u16x8*)((char*)bufA + ((e * 512 + c * 16) ^ ((e & 7) << 4))) = o;
    }
    // ---- stage edge_attr (+radial in col 51)
#pragma unroll
    for (int t = 0; t < 8; ++t) {
        int li = t * 512 + j;
        int row = li >> 6, k = li & 63;
        float v = (k < 51) ? eattr[(size_t)es_s[row] * 51 + k] : (k == 51 ? rad_s[row] : 0.f);
        int byte = (row * 128 + k * 2) ^ ((row & 7) << 4);
        attr[byte >> 1] = f2bf(v);
    }
    __syncthreads();

    f32x4 acc[2][4];

    // ---- stage 1: attr/radial MFMA (K=64) + bias + xsum (in place), silu
#pragma unroll
    for (int mt = 0; mt < 2; ++mt)
#pragma unroll
        for (int nt = 0; nt < 4; ++nt) acc[mt][nt] = z;
#pragma unroll
    for (int kc = 0; kc < 2; ++kc) {
        int r0 = rbase + ml, r1 = rbase + 16 + ml;
        bf16x8 a0 = *(const bf16x8*)((const char*)attr + ((r0 * 128 + (kc * 32 + g * 8) * 2) ^ ((r0 & 7) << 4)));
        bf16x8 a1 = *(const bf16x8*)((const char*)attr + ((r1 * 128 + (kc * 32 + g * 8) * 2) ^ ((r1 & 7) << 4)));
#pragma unroll
        for (int nt = 0; nt < 4; ++nt) {
            bf16x8 b = *(const bf16x8*)&e1pt[(size_t)(n0 + nt * 16 + ml) * 64 + kc * 32 + g * 8];
            acc[0][nt] = mfma16(a0, b, acc[0][nt]);
            acc[1][nt] = mfma16(a1, b, acc[1][nt]);
        }
    }
#pragma unroll
    for (int nt = 0; nt < 4; ++nt) {
        int col = n0 + nt * 16 + ml;
        float b1 = eb1[col];
#pragma unroll
        for (int mt = 0; mt < 2; ++mt)
#pragma unroll
            for (int i = 0; i < 4; ++i) {
                int row = rbase + mt * 16 + g * 4 + i;
                int off = actb(row, col) >> 1;
                float v = acc[mt][nt][i] + b1 + bf2f(bufA[off]);
                bufA[off] = f2bf(silu_f(v));        // same-thread in-place
            }
    }
    __syncthreads();

    // ---- stage 2 MFMA: e = act1 @ eW2 (K=256)
#pragma unroll
    for (int mt = 0; mt < 2; ++mt)
#pragma unroll
        for (int nt = 0; nt < 4; ++nt) acc[mt][nt] = z;
#pragma unroll
    for (int kc = 0; kc < 8; ++kc) {
        bf16x8 a0 = *(const bf16x8*)((const char*)bufA + actb(rbase + ml, kc * 32 + g * 8));
        bf16x8 a1 = *(const bf16x8*)((const char*)bufA + actb(rbase + 16 + ml, kc * 32 + g * 8));
#pragma unroll
        for (int nt = 0; nt < 4; ++nt) {
            bf16x8 b = *(const bf16x8*)&e2t[(size_t)(n0 + nt * 16 + ml) * 256 + kc * 32 + g * 8];
            acc[0][nt] = mfma16(a0, b, acc[0][nt]);
            acc[1][nt] = mfma16(a1, b, acc[1][nt]);
        }
    }
    __syncthreads();   // all act1 reads complete before overwrite
#pragma unroll
    for (int nt = 0; nt < 4; ++nt) {
        int col = n0 + nt * 16 + ml;
        float b2 = eb2[col];
#pragma unroll
        for (int mt = 0; mt < 2; ++mt)
#pragma unroll
            for (int i = 0; i < 4; ++i) {
                int row = rbase + mt * 16 + g * 4 + i;
                bufA[actb(row, col) >> 1] = f2bf(silu_f(acc[mt][nt][i] + b2));
            }
    }
    __syncthreads();

    // ---- run-length agg_node: thread owns (col, 32-row segment); rows
    // sorted -> one atomic per run. Branch wave-uniform (col varies in wave).
    {
        int col = j & 255, m0 = (j >> 8) << 5;
        int cur = ri_s[m0];
        float s = bf2f(bufA[actb(m0, col) >> 1]);
        for (int m = m0 + 1; m < m0 + 32; ++m) {
            int r = ri_s[m];
            float v = bf2f(bufA[actb(m, col) >> 1]);
            if (r != cur) {
                atomicAdd(&agg_node[(size_t)cur * 256 + col], s);
                s = 0.f; cur = r;
            }
            s += v;
        }
        atomicAdd(&agg_node[(size_t)cur * 256 + col], s);
    }

    // ---- stage 3: u = clip((silu(act2 @ cW1 + cb1)) . cW2)
#pragma unroll
    for (int mt = 0; mt < 2; ++mt)
#pragma unroll
        for (int nt = 0; nt < 4; ++nt) acc[mt][nt] = z;
#pragma unroll
    for (int kc = 0; kc < 8; ++kc) {
        bf16x8 a0 = *(const bf16x8*)((const char*)bufA + actb(rbase + ml, kc * 32 + g * 8));
        bf16x8 a1 = *(const bf16x8*)((const char*)bufA + actb(rbase + 16 + ml, kc * 32 + g * 8));
#pragma unroll
        for (int nt = 0; nt < 4; ++nt) {
            bf16x8 b = *(const bf16x8*)&c1t[(size_t)(n0 + nt * 16 + ml) * 256 + kc * 32 + g * 8];
            acc[0][nt] = mfma16(a0, b, acc[0][nt]);
            acc[1][nt] = mfma16(a1, b, acc[1][nt]);
        }
    }
    float p[2][4] = {{0.f, 0.f, 0.f, 0.f}, {0.f, 0.f, 0.f, 0.f}};
#pragma unroll
    for (int nt = 0; nt < 4; ++nt) {
        int col = n0 + nt * 16 + ml;
        float b3 = cb1[col];
        float w2 = cW2[col];
#pragma unroll
        for (int mt = 0; mt < 2; ++mt)
#pragma unroll
            for (int i = 0; i < 4; ++i)
                p[mt][i] += silu_f(acc[mt][nt][i] + b3) * w2;
    }
#pragma unroll
    for (int mt = 0; mt < 2; ++mt)
#pragma unroll
        for (int i = 0; i < 4; ++i) {
            float v = p[mt][i];
            v += __shfl_xor(v, 1);
            v += __shfl_xor(v, 2);
            v += __shfl_xor(v, 4);
            v += __shfl_xor(v, 8);
            p[mt][i] = v;
        }
    if (ml == 0) {
#pragma unroll
        for (int mt = 0; mt < 2; ++mt)
#pragma unroll
            for (int i = 0; i < 4; ++i)
                red[(rbase + mt * 16 + g * 4 + i) * 4 + cg] = p[mt][i];
    }
    __syncthreads();
    if (j < EB) {
        float u = red[j * 4 + 0] + red[j * 4 + 1] + red[j * 4 + 2] + red[j * 4 + 3];
        u = fminf(fmaxf(u, -1.f), 1.f);
        int rr = ri_s[j];
        atomicAdd(&agg_coord[(size_t)rr * 3 + 0], u * dif_s[j][0]);
        atomicAdd(&agg_coord[(size_t)rr * 3 + 1], u * dif_s[j][1]);
        atomicAdd(&agg_coord[(size_t)rr * 3 + 2], u * dif_s[j][2]);
    }
}

// ---------------------------------------------------------------------------
// node kernel: h_new = silu([h,agg] @ nW1 + nb1) @ nW2 + nb2 ; pos update
// ---------------------------------------------------------------------------
__global__ __launch_bounds__(256) void node_kernel(
    const u16* __restrict__ Xb, const float* __restrict__ agg_node,
    const float* __restrict__ agg_coord, const float* __restrict__ pos,
    const u16* __restrict__ n1t, const float* __restrict__ nb1,
    const u16* __restrict__ n2t, const float* __restrict__ nb2,
    float* __restrict__ out)
{
    __shared__ u16 act1[32 * 256];
    __shared__ u16 act2[32 * 256];
    const int n0b = blockIdx.x * 32;
    const int j = threadIdx.x, wv = j >> 6, lane = j & 63;
    const int ml = lane & 15, g = lane >> 4;
    const int n0 = wv * 64;
    const f32x4 z = {0.f, 0.f, 0.f, 0.f};

    for (int li = j; li < 32 * 256; li += 256) {
        int r = li >> 8, c = li & 255;
        act1[actb(r, c) >> 1] = f2bf(agg_node[(size_t)(n0b + r) * 256 + c]);
    }
    __syncthreads();

    f32x4 acc[2][4];
#pragma unroll
    for (int mt = 0; mt < 2; ++mt)
#pragma unroll
        for (int nt = 0; nt < 4; ++nt) acc[mt][nt] = z;
    for (int kc = 0; kc < 8; ++kc) {
        bf16x8 a0 = *(const bf16x8*)((const char*)act1 + actb(ml, kc * 32 + g * 8));
        bf16x8 a1 = *(const bf16x8*)((const char*)act1 + actb(16 + ml, kc * 32 + g * 8));
#pragma unroll
        for (int nt = 0; nt < 4; ++nt) {
            bf16x8 b = *(const bf16x8*)&n1t[(size_t)(n0 + nt * 16 + ml) * 256 + kc * 32 + g * 8];
            acc[0][nt] = mfma16(a0, b, acc[0][nt]);
            acc[1][nt] = mfma16(a1, b, acc[1][nt]);
        }
    }
#pragma unroll
    for (int mt = 0; mt < 2; ++mt)
#pragma unroll
        for (int nt = 0; nt < 4; ++nt) {
            int col = n0 + nt * 16 + ml;
            float b1 = nb1[col];
#pragma unroll
            for (int i = 0; i < 4; ++i) {
                int m = mt * 16 + g * 4 + i;
                float v = acc[mt][nt][i] + b1 + bf2f(Xb[(size_t)(n0b + m) * 768 + 512 + col]);
                act2[actb(m, col) >> 1] = f2bf(silu_f(v));
            }
        }
    __syncthreads();
#pragma unroll
    for (int mt = 0; mt < 2; ++mt)
#pragma unroll
        for (int nt = 0; nt < 4; ++nt) acc[mt][nt] = z;
    for (int kc = 0; kc < 8; ++kc) {
        bf16x8 a0 = *(const bf16x8*)((const char*)act2 + actb(ml, kc * 32 + g * 8));
        bf16x8 a1 = *(const bf16x8*)((const char*)act2 + actb(16 + ml, kc * 32 + g * 8));
#pragma unroll
        for (int nt = 0; nt < 4; ++nt) {
            bf16x8 b = *(const bf16x8*)&n2t[(size_t)(n0 + nt * 16 + ml) * 256 + kc * 32 + g * 8];
            acc[0][nt] = mfma16(a0, b, acc[0][nt]);
            acc[1][nt] = mfma16(a1, b, acc[1][nt]);
        }
    }
#pragma unroll
    for (int mt = 0; mt < 2; ++mt)
#pragma unroll
        for (int nt = 0; nt < 4; ++nt) {
            int col = n0 + nt * 16 + ml;
            float b2 = nb2[col];
#pragma unroll
            for (int i = 0; i < 4; ++i) {
                int row = n0b + mt * 16 + g * 4 + i;
                if (row < N_NODES)
                    out[(size_t)row * 256 + col] = acc[mt][nt][i] + b2;
            }
        }
    if (j < 96) {
        int idx = n0b * 3 + j;
        if (idx < N_NODES * 3)
            out[(size_t)N_NODES * 256 + idx] = pos[idx] + agg_coord[idx];
    }
}

// ---------------------------------------------------------------------------
extern "C" void kernel_launch(void* const* d_in, const int* in_sizes, int n_in,
                              void* d_out, int out_size, void* d_ws, size_t ws_size,
                              hipStream_t stream)
{
    (void)in_sizes; (void)n_in; (void)out_size; (void)ws_size;
    const float* h     = (const float*)d_in[0];
    const int*   eidx  = (const int*)d_in[1];
    const float* eattr = (const float*)d_in[2];
    const float* pos   = (const float*)d_in[3];
    const float* eW1   = (const float*)d_in[4];
    const float* eb1   = (const float*)d_in[5];
    const float* eW2   = (const float*)d_in[6];
    const float* eb2   = (const float*)d_in[7];
    const float* cW1   = (const float*)d_in[8];
    const float* cb1   = (const float*)d_in[9];
    const float* cW2   = (const float*)d_in[10];
    const float* nW1   = (const float*)d_in[11];
    const float* nb1   = (const float*)d_in[12];
    const float* nW2   = (const float*)d_in[13];
    const float* nb2   = (const float*)d_in[14];
    float* out = (float*)d_out;

    u16* Xb   = (u16*)d_ws;                                  // N_PAD*768 bf16
    u16* hb   = Xb + (size_t)N_PAD * 768;                    // N_PAD*512
    u16* Wt3  = hb + (size_t)N_PAD * 512;                    // 3*256*512
    u16* e1pt = Wt3 + 3 * 256 * 512;                         // 256*64
    u16* e2t  = e1pt + 256 * 64;                             // 256*256
    u16* c1t  = e2t + 256 * 256;
    u16* n1t  = c1t + 256 * 256;
    u16* n2t  = n1t + 256 * 256;
    float* agg_node  = (float*)(n2t + 256 * 256);            // N_PAD*256 f32
    float* agg_coord = agg_node + (size_t)N_PAD * 256;       // N_PAD*3  f32
    int* hist   = (int*)(agg_coord + (size_t)N_PAD * 3);     // N_PAD
    int* cnt    = hist + N_PAD;                              // N_PAD
    int* rowptr = cnt + N_PAD;                               // N_PAD+1
    int* eorder = rowptr + N_PAD + 1;                        // E

    hipMemsetAsync(agg_node, 0, (size_t)N_PAD * 259 * sizeof(float), stream);
    hipMemsetAsync(hist, 0, (size_t)2 * N_PAD * sizeof(int), stream);

    prep_weights<<<dim3(512, 8), 256, 0, stream>>>(eW1, eW2, cW1, nW1, nW2,
                                                   Wt3, e1pt, e2t, c1t, n1t, n2t);
    conv_h<<<(N_PAD * 512 / 8) / 256, 256, 0, stream>>>(h, hb);

    hist_kernel<<<(E_EDGES + 255) / 256, 256, 0, stream>>>(eidx, hist);
    scan_kernel<<<1, 256, 0, stream>>>(hist, rowptr);
    scatter_kernel<<<(E_EDGES + 255) / 256, 256, 0, stream>>>(eidx, rowptr, cnt, eorder);

    precompute_X<<<dim3(N_PAD / 32, 3), 256, 0, stream>>>(hb, Wt3, Xb);

    edge_kernel<<<E_EDGES / EB, 512, 0, stream>>>(
        Xb, pos, eidx, eattr, eorder, e1pt, eb1, e2t, eb2, c1t, cb1, cW2,
        agg_node, agg_coord);

    node_kernel<<<N_PAD / 32, 256, 0, stream>>>(
        Xb, agg_node, agg_coord, pos, n1t, nb1, n2t, nb2, out);
}

// Round 7
// 411.435 us; speedup vs baseline: 1.4393x; 1.1587x over previous
//
#include <hip/hip_runtime.h>
#include <hip/hip_bf16.h>

#define N_NODES 10000
#define N_PAD   10016
#define E_EDGES 160000
#define EB 32     // edges per block (edge kernel v4)
#define HID 256

typedef __attribute__((ext_vector_type(4))) float f32x4;
typedef __attribute__((ext_vector_type(8))) short bf16x8;
typedef __attribute__((ext_vector_type(8))) unsigned short u16x8;
typedef __attribute__((ext_vector_type(4))) unsigned u32x4;
typedef unsigned short u16;

__device__ __forceinline__ float silu_f(float x) { return x / (1.0f + __expf(-x)); }

__device__ __forceinline__ u16 f2bf(float f) {           // round-to-nearest-even
    unsigned x = __float_as_uint(f);
    unsigned r = x + 0x7FFFu + ((x >> 16) & 1u);
    return (u16)(r >> 16);
}
__device__ __forceinline__ float bf2f(u16 u) {
    return __uint_as_float(((unsigned)u) << 16);
}
// hw packed convert: dst = {lo: bf16(a), hi: bf16(b)}
__device__ __forceinline__ unsigned cvtpk(float a, float b) {
    unsigned r;
    asm("v_cvt_pk_bf16_f32 %0, %1, %2" : "=v"(r) : "v"(a), "v"(b));
    return r;
}
__device__ __forceinline__ f32x4 mfma16(bf16x8 a, bf16x8 b, f32x4 c) {
    return __builtin_amdgcn_mfma_f32_16x16x32_bf16(a, b, c, 0, 0, 0);
}
// swizzled byte offset into a [rows][256] u16 activation tile (stride 512B)
__device__ __forceinline__ int actb(int row, int elem) {
    return (row * 512 + elem * 2) ^ ((row & 7) << 4);
}

// ---------------------------------------------------------------------------
// prep: weight transposes -> bf16 [n][k] layouts
// ---------------------------------------------------------------------------
__global__ __launch_bounds__(256) void prep_weights(
    const float* __restrict__ eW1, const float* __restrict__ eW2,
    const float* __restrict__ cW1, const float* __restrict__ nW1,
    const float* __restrict__ nW2,
    u16* __restrict__ Wt3, u16* __restrict__ e1pt, u16* __restrict__ e2t,
    u16* __restrict__ c1t, u16* __restrict__ n1t, u16* __restrict__ n2t)
{
    const int y = blockIdx.y;
    const float* src; u16* dst; int Ks, Kd;
    switch (y) {
        case 0: src = eW1;                dst = Wt3;                Ks = 512; Kd = 512; break;
        case 1: src = eW1 + 512 * 256;    dst = Wt3 + 256 * 512;    Ks = 512; Kd = 512; break;
        case 2: src = nW1;                dst = Wt3 + 2 * 256 * 512; Ks = 512; Kd = 512; break;
        case 3: src = eW1 + 1024 * 256;   dst = e1pt;               Ks = 52;  Kd = 64;  break; // attr rows + radial row (1075)
        case 4: src = eW2;                dst = e2t;                Ks = 256; Kd = 256; break;
        case 5: src = cW1;                dst = c1t;                Ks = 256; Kd = 256; break;
        case 6: src = nW1 + 512 * 256;    dst = n1t;                Ks = 256; Kd = 256; break;
        default: src = nW2;               dst = n2t;                Ks = 256; Kd = 256; break;
    }
    int idx = blockIdx.x * 256 + threadIdx.x;
    if (idx < 256 * Kd) {
        int n = idx / Kd, k = idx - n * Kd;
        dst[idx] = (k < Ks) ? f2bf(src[(size_t)k * 256 + n]) : (u16)0;
    }
}

// h (f32) -> h_bf (bf16), zero-padded rows to N_PAD
__global__ __launch_bounds__(256) void conv_h(const float* __restrict__ h, u16* __restrict__ hb)
{
    size_t base = ((size_t)blockIdx.x * 256 + threadIdx.x) * 8;
    int row = (int)(base >> 9);
    u16x8 o;
    if (row < N_NODES) {
        const float4 f0 = *(const float4*)&h[base];
        const float4 f1 = *(const float4*)&h[base + 4];
        o[0] = f2bf(f0.x); o[1] = f2bf(f0.y); o[2] = f2bf(f0.z); o[3] = f2bf(f0.w);
        o[4] = f2bf(f1.x); o[5] = f2bf(f1.y); o[6] = f2bf(f1.z); o[7] = f2bf(f1.w);
    } else {
        o = (u16x8)0;
    }
    *(u16x8*)&hb[base] = o;
}

// ---------------------------------------------------------------------------
// counting sort of edges by destination row: hist -> scan -> scatter
// ---------------------------------------------------------------------------
__global__ __launch_bounds__(256) void hist_kernel(const int* __restrict__ row,
                                                   int* __restrict__ hist)
{
    int e = blockIdx.x * 256 + threadIdx.x;
    if (e < E_EDGES) atomicAdd(&hist[row[e]], 1);
}

#define SCAN_PER 40   // 256*40 >= N_PAD
__global__ __launch_bounds__(256) void scan_kernel(const int* __restrict__ hist,
                                                   int* __restrict__ rowptr)
{
    __shared__ int a[256];
    const int t = threadIdx.x;
    const int base = t * SCAN_PER;
    int s = 0;
    for (int i = 0; i < SCAN_PER; ++i) {
        int b = base + i;
        if (b < N_PAD) s += hist[b];
    }
    a[t] = s;
    __syncthreads();
    for (int off = 1; off < 256; off <<= 1) {
        int v = (t >= off) ? a[t - off] : 0;
        __syncthreads();
        a[t] += v;
        __syncthreads();
    }
    int run = a[t] - s;      // exclusive base for this thread's span
    for (int i = 0; i < SCAN_PER; ++i) {
        int b = base + i;
        if (b < N_PAD) { rowptr[b] = run; run += hist[b]; }
    }
    if (t == 255) rowptr[N_PAD] = a[255];
}

__global__ __launch_bounds__(256) void scatter_kernel(const int* __restrict__ row,
                                                      const int* __restrict__ rowptr,
                                                      int* __restrict__ cnt,
                                                      int* __restrict__ eorder)
{
    int e = blockIdx.x * 256 + threadIdx.x;
    if (e < E_EDGES) {
        int r = row[e];
        int p = rowptr[r] + atomicAdd(&cnt[r], 1);
        eorder[p] = e;
    }
}

// ---------------------------------------------------------------------------
// Xb[n][0:256]=h@eW1[:512], [256:512]=h@eW1[512:1024], [512:768]=h@nW1[:512] (bf16)
// ---------------------------------------------------------------------------
__global__ __launch_bounds__(256) void precompute_X(
    const u16* __restrict__ hb, const u16* __restrict__ Wt3, u16* __restrict__ Xb)
{
    const int n0b = blockIdx.x * 32;
    const int which = blockIdx.y;
    const int j = threadIdx.x, wv = j >> 6, lane = j & 63;
    const int ml = lane & 15, g = lane >> 4;
    const int n0 = wv * 64;
    const u16* W = Wt3 + (size_t)which * 256 * 512;

    f32x4 acc[2][4];
    const f32x4 z = {0.f, 0.f, 0.f, 0.f};
#pragma unroll
    for (int mt = 0; mt < 2; ++mt)
#pragma unroll
        for (int nt = 0; nt < 4; ++nt) acc[mt][nt] = z;

    for (int kc = 0; kc < 16; ++kc) {
        bf16x8 a0 = *(const bf16x8*)&hb[(size_t)(n0b + ml) * 512 + kc * 32 + g * 8];
        bf16x8 a1 = *(const bf16x8*)&hb[(size_t)(n0b + 16 + ml) * 512 + kc * 32 + g * 8];
#pragma unroll
        for (int nt = 0; nt < 4; ++nt) {
            bf16x8 b = *(const bf16x8*)&W[(size_t)(n0 + nt * 16 + ml) * 512 + kc * 32 + g * 8];
            acc[0][nt] = mfma16(a0, b, acc[0][nt]);
            acc[1][nt] = mfma16(a1, b, acc[1][nt]);
        }
    }
#pragma unroll
    for (int mt = 0; mt < 2; ++mt)
#pragma unroll
        for (int nt = 0; nt < 4; ++nt) {
            int col = n0 + nt * 16 + ml;
#pragma unroll
            for (int i = 0; i < 4; ++i) {
                int row = n0b + mt * 16 + g * 4 + i;
                Xb[(size_t)row * 768 + which * 256 + col] = f2bf(acc[mt][nt][i]);
            }
        }
}

// ---------------------------------------------------------------------------
// edge kernel v4: 32 sorted edges/block, 256 thr (4 waves, col-split).
// Single 16KB LDS tile in place (xsum->act1->act2); attr frags in registers.
// LDS ~17.8KB -> high occupancy. acc = 2x4 f32x4 + af 16 VGPR.
// ---------------------------------------------------------------------------
__global__ __launch_bounds__(256, 5) void edge_kernel(
    const u16* __restrict__ Xb, const float* __restrict__ pos,
    const int* __restrict__ eidx, const float* __restrict__ eattr,
    const int* __restrict__ eorder,
    const u16* __restrict__ e1pt, const float* __restrict__ eb1,
    const u16* __restrict__ e2t, const float* __restrict__ eb2,
    const u16* __restrict__ c1t, const float* __restrict__ cb1,
    const float* __restrict__ cW2,
    float* __restrict__ agg_node, float* __restrict__ agg_coord)
{
    __shared__ u16 bufA[EB * 256];    // 16 KB, xsum -> act1 -> act2 in place
    __shared__ int ri_s[EB], ci_s[EB], es_s[EB];
    __shared__ float rad_s[EB], dif_s[EB][3];
    __shared__ float red[EB * 4];

    const int j = threadIdx.x, w = j >> 6, lane = j & 63;
    const int ml = lane & 15, g = lane >> 4;
    const int n0 = w * 64;            // this wave's col group
    const f32x4 z = {0.f, 0.f, 0.f, 0.f};

    // bijective XCD-chunked swizzle: consecutive sorted-edge blocks share L2
    const int nwg = gridDim.x;
    const int qq = nwg >> 3, r8 = nwg & 7;
    const int xcd = blockIdx.x & 7, sub = blockIdx.x >> 3;
    const int wg = (xcd < r8 ? xcd * (qq + 1) : r8 * (qq + 1) + (xcd - r8) * qq) + sub;
    const int e0 = wg * EB;

    if (j < EB) {
        int e = eorder[e0 + j];
        es_s[j] = e;
        int r = eidx[e], c = eidx[E_EDGES + e];
        ri_s[j] = r; ci_s[j] = c;
        float dx = pos[r * 3 + 0] - pos[c * 3 + 0];
        float dy = pos[r * 3 + 1] - pos[c * 3 + 1];
        float dz = pos[r * 3 + 2] - pos[c * 3 + 2];
        dif_s[j][0] = dx; dif_s[j][1] = dy; dif_s[j][2] = dz;
        rad_s[j] = sqrtf(dx * dx + dy * dy + dz * dz) + 1e-8f;
    }
    __syncthreads();

    // ---- cooperative gather: bufA[e][:] = Xr[ri[e]] + Xc[ci[e]] (bf16)
#pragma unroll
    for (int t = 0; t < 4; ++t) {
        int li = t * 256 + j;           // (edge, 16B-chunk)
        int e = li >> 5, c = li & 31;
        const u16x8 xr = *(const u16x8*)&Xb[(size_t)ri_s[e] * 768 + c * 8];
        const u16x8 xc = *(const u16x8*)&Xb[(size_t)ci_s[e] * 768 + 256 + c * 8];
        u32x4 o;
#pragma unroll
        for (int k = 0; k < 4; ++k)
            o[k] = cvtpk(bf2f(xr[2 * k]) + bf2f(xc[2 * k]),
                         bf2f(xr[2 * k + 1]) + bf2f(xc[2 * k + 1]));
        *(u32x4*)((char*)bufA + ((e * 512 + c * 16) ^ ((e & 7) << 4))) = o;
    }

    // ---- attr/radial A-fragments built in registers (rows = ml, 16+ml)
    bf16x8 af[2][2];
#pragma unroll
    for (int mt = 0; mt < 2; ++mt) {
        int row = mt * 16 + ml;
        const float* ap = eattr + (size_t)es_s[row] * 51;
        float rd = rad_s[row];
        int k0 = g * 8;
        u32x4 f0, f1;
#pragma unroll
        for (int t = 0; t < 4; ++t)
            f0[t] = cvtpk(ap[k0 + 2 * t], ap[k0 + 2 * t + 1]);
        if (g < 2) {
            int k1 = 32 + g * 8;
#pragma unroll
            for (int t = 0; t < 4; ++t)
                f1[t] = cvtpk(ap[k1 + 2 * t], ap[k1 + 2 * t + 1]);
        } else if (g == 2) {
            f1[0] = cvtpk(ap[48], ap[49]);
            f1[1] = cvtpk(ap[50], rd);
            f1[2] = 0u; f1[3] = 0u;
        } else {
            f1 = (u32x4)0u;
        }
        af[mt][0] = *(bf16x8*)&f0;
        af[mt][1] = *(bf16x8*)&f1;
    }
    __syncthreads();

    f32x4 acc[2][4];

    // ---- stage 1: attr/radial MFMA (K=64) + bias + xsum (in place), silu
#pragma unroll
    for (int mt = 0; mt < 2; ++mt)
#pragma unroll
        for (int nt = 0; nt < 4; ++nt) acc[mt][nt] = z;
#pragma unroll
    for (int kc = 0; kc < 2; ++kc)
#pragma unroll
        for (int nt = 0; nt < 4; ++nt) {
            bf16x8 b = *(const bf16x8*)&e1pt[(size_t)(n0 + nt * 16 + ml) * 64 + kc * 32 + g * 8];
            acc[0][nt] = mfma16(af[0][kc], b, acc[0][nt]);
            acc[1][nt] = mfma16(af[1][kc], b, acc[1][nt]);
        }
#pragma unroll
    for (int nt = 0; nt < 4; ++nt) {
        int col = n0 + nt * 16 + ml;
        float b1 = eb1[col];
#pragma unroll
        for (int mt = 0; mt < 2; ++mt)
#pragma unroll
            for (int i = 0; i < 4; ++i) {
                int row = mt * 16 + g * 4 + i;
                int off = actb(row, col) >> 1;
                float v = acc[mt][nt][i] + b1 + bf2f(bufA[off]);
                bufA[off] = f2bf(silu_f(v));        // same-thread in-place
            }
    }
    __syncthreads();

    // ---- stage 2 MFMA: e = act1 @ eW2 (K=256)
#pragma unroll
    for (int mt = 0; mt < 2; ++mt)
#pragma unroll
        for (int nt = 0; nt < 4; ++nt) acc[mt][nt] = z;
#pragma unroll
    for (int kc = 0; kc < 8; ++kc) {
        bf16x8 a0 = *(const bf16x8*)((const char*)bufA + actb(ml, kc * 32 + g * 8));
        bf16x8 a1 = *(const bf16x8*)((const char*)bufA + actb(16 + ml, kc * 32 + g * 8));
#pragma unroll
        for (int nt = 0; nt < 4; ++nt) {
            bf16x8 b = *(const bf16x8*)&e2t[(size_t)(n0 + nt * 16 + ml) * 256 + kc * 32 + g * 8];
            acc[0][nt] = mfma16(a0, b, acc[0][nt]);
            acc[1][nt] = mfma16(a1, b, acc[1][nt]);
        }
    }
    __syncthreads();   // all act1 reads complete before overwrite
#pragma unroll
    for (int nt = 0; nt < 4; ++nt) {
        int col = n0 + nt * 16 + ml;
        float b2 = eb2[col];
#pragma unroll
        for (int mt = 0; mt < 2; ++mt)
#pragma unroll
            for (int i = 0; i < 4; ++i) {
                int row = mt * 16 + g * 4 + i;
                bufA[actb(row, col) >> 1] = f2bf(silu_f(acc[mt][nt][i] + b2));
            }
    }
    __syncthreads();

    // ---- stage 3 MFMA: c = act2 @ cW1 (K=256)
#pragma unroll
    for (int mt = 0; mt < 2; ++mt)
#pragma unroll
        for (int nt = 0; nt < 4; ++nt) acc[mt][nt] = z;
#pragma unroll
    for (int kc = 0; kc < 8; ++kc) {
        bf16x8 a0 = *(const bf16x8*)((const char*)bufA + actb(ml, kc * 32 + g * 8));
        bf16x8 a1 = *(const bf16x8*)((const char*)bufA + actb(16 + ml, kc * 32 + g * 8));
#pragma unroll
        for (int nt = 0; nt < 4; ++nt) {
            bf16x8 b = *(const bf16x8*)&c1t[(size_t)(n0 + nt * 16 + ml) * 256 + kc * 32 + g * 8];
            acc[0][nt] = mfma16(a0, b, acc[0][nt]);
            acc[1][nt] = mfma16(a1, b, acc[1][nt]);
        }
    }

    // ---- run-length agg_node: thread owns one col; rows sorted -> one
    // atomic per distinct destination row.
    {
        int cur = ri_s[0];
        float s = bf2f(bufA[actb(0, j) >> 1]);
        for (int m = 1; m < EB; ++m) {
            int r = ri_s[m];
            float v = bf2f(bufA[actb(m, j) >> 1]);
            if (r != cur) {
                atomicAdd(&agg_node[(size_t)cur * 256 + j], s);
                s = 0.f; cur = r;
            }
            s += v;
        }
        atomicAdd(&agg_node[(size_t)cur * 256 + j], s);
    }

    // ---- stage 3 epilogue: u = clip((silu(c + cb1)) . cW2)
    float p[2][4] = {{0.f, 0.f, 0.f, 0.f}, {0.f, 0.f, 0.f, 0.f}};
#pragma unroll
    for (int nt = 0; nt < 4; ++nt) {
        int col = n0 + nt * 16 + ml;
        float b3 = cb1[col];
        float w2 = cW2[col];
#pragma unroll
        for (int mt = 0; mt < 2; ++mt)
#pragma unroll
            for (int i = 0; i < 4; ++i)
                p[mt][i] += silu_f(acc[mt][nt][i] + b3) * w2;
    }
#pragma unroll
    for (int mt = 0; mt < 2; ++mt)
#pragma unroll
        for (int i = 0; i < 4; ++i) {
            float v = p[mt][i];
            v += __shfl_xor(v, 1);
            v += __shfl_xor(v, 2);
            v += __shfl_xor(v, 4);
            v += __shfl_xor(v, 8);
            p[mt][i] = v;
        }
    if (ml == 0) {
#pragma unroll
        for (int mt = 0; mt < 2; ++mt)
#pragma unroll
            for (int i = 0; i < 4; ++i)
                red[(mt * 16 + g * 4 + i) * 4 + w] = p[mt][i];
    }
    __syncthreads();
    if (j < EB) {
        float u = red[j * 4 + 0] + red[j * 4 + 1] + red[j * 4 + 2] + red[j * 4 + 3];
        u = fminf(fmaxf(u, -1.f), 1.f);
        int rr = ri_s[j];
        atomicAdd(&agg_coord[(size_t)rr * 3 + 0], u * dif_s[j][0]);
        atomicAdd(&agg_coord[(size_t)rr * 3 + 1], u * dif_s[j][1]);
        atomicAdd(&agg_coord[(size_t)rr * 3 + 2], u * dif_s[j][2]);
    }
}

// ---------------------------------------------------------------------------
// node kernel: h_new = silu([h,agg] @ nW1 + nb1) @ nW2 + nb2 ; pos update
// ---------------------------------------------------------------------------
__global__ __launch_bounds__(256) void node_kernel(
    const u16* __restrict__ Xb, const float* __restrict__ agg_node,
    const float* __restrict__ agg_coord, const float* __restrict__ pos,
    const u16* __restrict__ n1t, const float* __restrict__ nb1,
    const u16* __restrict__ n2t, const float* __restrict__ nb2,
    float* __restrict__ out)
{
    __shared__ u16 act1[32 * 256];
    __shared__ u16 act2[32 * 256];
    const int n0b = blockIdx.x * 32;
    const int j = threadIdx.x, wv = j >> 6, lane = j & 63;
    const int ml = lane & 15, g = lane >> 4;
    const int n0 = wv * 64;
    const f32x4 z = {0.f, 0.f, 0.f, 0.f};

    for (int li = j; li < 32 * 256; li += 256) {
        int r = li >> 8, c = li & 255;
        act1[actb(r, c) >> 1] = f2bf(agg_node[(size_t)(n0b + r) * 256 + c]);
    }
    __syncthreads();

    f32x4 acc[2][4];
#pragma unroll
    for (int mt = 0; mt < 2; ++mt)
#pragma unroll
        for (int nt = 0; nt < 4; ++nt) acc[mt][nt] = z;
    for (int kc = 0; kc < 8; ++kc) {
        bf16x8 a0 = *(const bf16x8*)((const char*)act1 + actb(ml, kc * 32 + g * 8));
        bf16x8 a1 = *(const bf16x8*)((const char*)act1 + actb(16 + ml, kc * 32 + g * 8));
#pragma unroll
        for (int nt = 0; nt < 4; ++nt) {
            bf16x8 b = *(const bf16x8*)&n1t[(size_t)(n0 + nt * 16 + ml) * 256 + kc * 32 + g * 8];
            acc[0][nt] = mfma16(a0, b, acc[0][nt]);
            acc[1][nt] = mfma16(a1, b, acc[1][nt]);
        }
    }
#pragma unroll
    for (int mt = 0; mt < 2; ++mt)
#pragma unroll
        for (int nt = 0; nt < 4; ++nt) {
            int col = n0 + nt * 16 + ml;
            float b1 = nb1[col];
#pragma unroll
            for (int i = 0; i < 4; ++i) {
                int m = mt * 16 + g * 4 + i;
                float v = acc[mt][nt][i] + b1 + bf2f(Xb[(size_t)(n0b + m) * 768 + 512 + col]);
                act2[actb(m, col) >> 1] = f2bf(silu_f(v));
            }
        }
    __syncthreads();
#pragma unroll
    for (int mt = 0; mt < 2; ++mt)
#pragma unroll
        for (int nt = 0; nt < 4; ++nt) acc[mt][nt] = z;
    for (int kc = 0; kc < 8; ++kc) {
        bf16x8 a0 = *(const bf16x8*)((const char*)act2 + actb(ml, kc * 32 + g * 8));
        bf16x8 a1 = *(const bf16x8*)((const char*)act2 + actb(16 + ml, kc * 32 + g * 8));
#pragma unroll
        for (int nt = 0; nt < 4; ++nt) {
            bf16x8 b = *(const bf16x8*)&n2t[(size_t)(n0 + nt * 16 + ml) * 256 + kc * 32 + g * 8];
            acc[0][nt] = mfma16(a0, b, acc[0][nt]);
            acc[1][nt] = mfma16(a1, b, acc[1][nt]);
        }
    }
#pragma unroll
    for (int mt = 0; mt < 2; ++mt)
#pragma unroll
        for (int nt = 0; nt < 4; ++nt) {
            int col = n0 + nt * 16 + ml;
            float b2 = nb2[col];
#pragma unroll
            for (int i = 0; i < 4; ++i) {
                int row = n0b + mt * 16 + g * 4 + i;
                if (row < N_NODES)
                    out[(size_t)row * 256 + col] = acc[mt][nt][i] + b2;
            }
        }
    if (j < 96) {
        int idx = n0b * 3 + j;
        if (idx < N_NODES * 3)
            out[(size_t)N_NODES * 256 + idx] = pos[idx] + agg_coord[idx];
    }
}

// ---------------------------------------------------------------------------
extern "C" void kernel_launch(void* const* d_in, const int* in_sizes, int n_in,
                              void* d_out, int out_size, void* d_ws, size_t ws_size,
                              hipStream_t stream)
{
    (void)in_sizes; (void)n_in; (void)out_size; (void)ws_size;
    const float* h     = (const float*)d_in[0];
    const int*   eidx  = (const int*)d_in[1];
    const float* eattr = (const float*)d_in[2];
    const float* pos   = (const float*)d_in[3];
    const float* eW1   = (const float*)d_in[4];
    const float* eb1   = (const float*)d_in[5];
    const float* eW2   = (const float*)d_in[6];
    const float* eb2   = (const float*)d_in[7];
    const float* cW1   = (const float*)d_in[8];
    const float* cb1   = (const float*)d_in[9];
    const float* cW2   = (const float*)d_in[10];
    const float* nW1   = (const float*)d_in[11];
    const float* nb1   = (const float*)d_in[12];
    const float* nW2   = (const float*)d_in[13];
    const float* nb2   = (const float*)d_in[14];
    float* out = (float*)d_out;

    u16* Xb   = (u16*)d_ws;                                  // N_PAD*768 bf16
    u16* hb   = Xb + (size_t)N_PAD * 768;                    // N_PAD*512
    u16* Wt3  = hb + (size_t)N_PAD * 512;                    // 3*256*512
    u16* e1pt = Wt3 + 3 * 256 * 512;                         // 256*64
    u16* e2t  = e1pt + 256 * 64;                             // 256*256
    u16* c1t  = e2t + 256 * 256;
    u16* n1t  = c1t + 256 * 256;
    u16* n2t  = n1t + 256 * 256;
    float* agg_node  = (float*)(n2t + 256 * 256);            // N_PAD*256 f32
    float* agg_coord = agg_node + (size_t)N_PAD * 256;       // N_PAD*3  f32
    int* hist   = (int*)(agg_coord + (size_t)N_PAD * 3);     // N_PAD
    int* cnt    = hist + N_PAD;                              // N_PAD
    int* rowptr = cnt + N_PAD;                               // N_PAD+1
    int* eorder = rowptr + N_PAD + 1;                        // E

    hipMemsetAsync(agg_node, 0, (size_t)N_PAD * 259 * sizeof(float), stream);
    hipMemsetAsync(hist, 0, (size_t)2 * N_PAD * sizeof(int), stream);

    prep_weights<<<dim3(512, 8), 256, 0, stream>>>(eW1, eW2, cW1, nW1, nW2,
                                                   Wt3, e1pt, e2t, c1t, n1t, n2t);
    conv_h<<<(N_PAD * 512 / 8) / 256, 256, 0, stream>>>(h, hb);

    hist_kernel<<<(E_EDGES + 255) / 256, 256, 0, stream>>>(eidx, hist);
    scan_kernel<<<1, 256, 0, stream>>>(hist, rowptr);
    scatter_kernel<<<(E_EDGES + 255) / 256, 256, 0, stream>>>(eidx, rowptr, cnt, eorder);

    precompute_X<<<dim3(N_PAD / 32, 3), 256, 0, stream>>>(hb, Wt3, Xb);

    edge_kernel<<<E_EDGES / EB, 256, 0, stream>>>(
        Xb, pos, eidx, eattr, eorder, e1pt, eb1, e2t, eb2, c1t, cb1, cW2,
        agg_node, agg_coord);

    node_kernel<<<N_PAD / 32, 256, 0, stream>>>(
        Xb, agg_node, agg_coord, pos, n1t, nb1, n2t, nb2, out);
}

// Round 8
// 409.811 us; speedup vs baseline: 1.4450x; 1.0040x over previous
//
#include <hip/hip_runtime.h>
#include <hip/hip_bf16.h>

#define N_NODES 10000
#define N_PAD   10016
#define E_EDGES 160000
#define EB 32     // edges per block (edge kernel v5)
#define HID 256

typedef __attribute__((ext_vector_type(4))) float f32x4;
typedef __attribute__((ext_vector_type(8))) short bf16x8;
typedef __attribute__((ext_vector_type(8))) unsigned short u16x8;
typedef __attribute__((ext_vector_type(4))) unsigned u32x4;
typedef unsigned short u16;

__device__ __forceinline__ float silu_f(float x) { return x / (1.0f + __expf(-x)); }

__device__ __forceinline__ u16 f2bf(float f) {           // round-to-nearest-even
    unsigned x = __float_as_uint(f);
    unsigned r = x + 0x7FFFu + ((x >> 16) & 1u);
    return (u16)(r >> 16);
}
__device__ __forceinline__ float bf2f(u16 u) {
    return __uint_as_float(((unsigned)u) << 16);
}
// hw packed convert: dst = {lo: bf16(a), hi: bf16(b)}
__device__ __forceinline__ unsigned cvtpk(float a, float b) {
    unsigned r;
    asm("v_cvt_pk_bf16_f32 %0, %1, %2" : "=v"(r) : "v"(a), "v"(b));
    return r;
}
__device__ __forceinline__ f32x4 mfma16(bf16x8 a, bf16x8 b, f32x4 c) {
    return __builtin_amdgcn_mfma_f32_16x16x32_bf16(a, b, c, 0, 0, 0);
}
// swizzled byte offset into a [rows][256] u16 activation tile (stride 512B)
__device__ __forceinline__ int actb(int row, int elem) {
    return (row * 512 + elem * 2) ^ ((row & 7) << 4);
}

// ---------------------------------------------------------------------------
// prep: weight transposes -> bf16 [n][k] layouts
// ---------------------------------------------------------------------------
__global__ __launch_bounds__(256) void prep_weights(
    const float* __restrict__ eW1, const float* __restrict__ eW2,
    const float* __restrict__ cW1, const float* __restrict__ nW1,
    const float* __restrict__ nW2,
    u16* __restrict__ Wt3, u16* __restrict__ e1pt, u16* __restrict__ e2t,
    u16* __restrict__ c1t, u16* __restrict__ n1t, u16* __restrict__ n2t)
{
    const int y = blockIdx.y;
    const float* src; u16* dst; int Ks, Kd;
    switch (y) {
        case 0: src = eW1;                dst = Wt3;                Ks = 512; Kd = 512; break;
        case 1: src = eW1 + 512 * 256;    dst = Wt3 + 256 * 512;    Ks = 512; Kd = 512; break;
        case 2: src = nW1;                dst = Wt3 + 2 * 256 * 512; Ks = 512; Kd = 512; break;
        case 3: src = eW1 + 1024 * 256;   dst = e1pt;               Ks = 52;  Kd = 64;  break; // attr rows + radial row (1075)
        case 4: src = eW2;                dst = e2t;                Ks = 256; Kd = 256; break;
        case 5: src = cW1;                dst = c1t;                Ks = 256; Kd = 256; break;
        case 6: src = nW1 + 512 * 256;    dst = n1t;                Ks = 256; Kd = 256; break;
        default: src = nW2;               dst = n2t;                Ks = 256; Kd = 256; break;
    }
    int idx = blockIdx.x * 256 + threadIdx.x;
    if (idx < 256 * Kd) {
        int n = idx / Kd, k = idx - n * Kd;
        dst[idx] = (k < Ks) ? f2bf(src[(size_t)k * 256 + n]) : (u16)0;
    }
}

// h (f32) -> h_bf (bf16), zero-padded rows to N_PAD
__global__ __launch_bounds__(256) void conv_h(const float* __restrict__ h, u16* __restrict__ hb)
{
    size_t base = ((size_t)blockIdx.x * 256 + threadIdx.x) * 8;
    int row = (int)(base >> 9);
    u16x8 o;
    if (row < N_NODES) {
        const float4 f0 = *(const float4*)&h[base];
        const float4 f1 = *(const float4*)&h[base + 4];
        o[0] = f2bf(f0.x); o[1] = f2bf(f0.y); o[2] = f2bf(f0.z); o[3] = f2bf(f0.w);
        o[4] = f2bf(f1.x); o[5] = f2bf(f1.y); o[6] = f2bf(f1.z); o[7] = f2bf(f1.w);
    } else {
        o = (u16x8)0;
    }
    *(u16x8*)&hb[base] = o;
}

// ---------------------------------------------------------------------------
// counting sort of edges by destination row: hist -> scan -> scatter
// ---------------------------------------------------------------------------
__global__ __launch_bounds__(256) void hist_kernel(const int* __restrict__ row,
                                                   int* __restrict__ hist)
{
    int e = blockIdx.x * 256 + threadIdx.x;
    if (e < E_EDGES) atomicAdd(&hist[row[e]], 1);
}

#define SCAN_PER 40   // 256*40 >= N_PAD
__global__ __launch_bounds__(256) void scan_kernel(const int* __restrict__ hist,
                                                   int* __restrict__ rowptr)
{
    __shared__ int a[256];
    const int t = threadIdx.x;
    const int base = t * SCAN_PER;
    int s = 0;
    for (int i = 0; i < SCAN_PER; ++i) {
        int b = base + i;
        if (b < N_PAD) s += hist[b];
    }
    a[t] = s;
    __syncthreads();
    for (int off = 1; off < 256; off <<= 1) {
        int v = (t >= off) ? a[t - off] : 0;
        __syncthreads();
        a[t] += v;
        __syncthreads();
    }
    int run = a[t] - s;      // exclusive base for this thread's span
    for (int i = 0; i < SCAN_PER; ++i) {
        int b = base + i;
        if (b < N_PAD) { rowptr[b] = run; run += hist[b]; }
    }
    if (t == 255) rowptr[N_PAD] = a[255];
}

__global__ __launch_bounds__(256) void scatter_kernel(const int* __restrict__ row,
                                                      const int* __restrict__ rowptr,
                                                      int* __restrict__ cnt,
                                                      int* __restrict__ eorder)
{
    int e = blockIdx.x * 256 + threadIdx.x;
    if (e < E_EDGES) {
        int r = row[e];
        int p = rowptr[r] + atomicAdd(&cnt[r], 1);
        eorder[p] = e;
    }
}

// ---------------------------------------------------------------------------
// Xb[n][0:256]=h@eW1[:512], [256:512]=h@eW1[512:1024], [512:768]=h@nW1[:512] (bf16)
// ---------------------------------------------------------------------------
__global__ __launch_bounds__(256) void precompute_X(
    const u16* __restrict__ hb, const u16* __restrict__ Wt3, u16* __restrict__ Xb)
{
    const int n0b = blockIdx.x * 32;
    const int which = blockIdx.y;
    const int j = threadIdx.x, wv = j >> 6, lane = j & 63;
    const int ml = lane & 15, g = lane >> 4;
    const int n0 = wv * 64;
    const u16* W = Wt3 + (size_t)which * 256 * 512;

    f32x4 acc[2][4];
    const f32x4 z = {0.f, 0.f, 0.f, 0.f};
#pragma unroll
    for (int mt = 0; mt < 2; ++mt)
#pragma unroll
        for (int nt = 0; nt < 4; ++nt) acc[mt][nt] = z;

    for (int kc = 0; kc < 16; ++kc) {
        bf16x8 a0 = *(const bf16x8*)&hb[(size_t)(n0b + ml) * 512 + kc * 32 + g * 8];
        bf16x8 a1 = *(const bf16x8*)&hb[(size_t)(n0b + 16 + ml) * 512 + kc * 32 + g * 8];
#pragma unroll
        for (int nt = 0; nt < 4; ++nt) {
            bf16x8 b = *(const bf16x8*)&W[(size_t)(n0 + nt * 16 + ml) * 512 + kc * 32 + g * 8];
            acc[0][nt] = mfma16(a0, b, acc[0][nt]);
            acc[1][nt] = mfma16(a1, b, acc[1][nt]);
        }
    }
#pragma unroll
    for (int mt = 0; mt < 2; ++mt)
#pragma unroll
        for (int nt = 0; nt < 4; ++nt) {
            int col = n0 + nt * 16 + ml;
#pragma unroll
            for (int i = 0; i < 4; ++i) {
                int row = n0b + mt * 16 + g * 4 + i;
                Xb[(size_t)row * 768 + which * 256 + col] = f2bf(acc[mt][nt][i]);
            }
        }
}

// ---------------------------------------------------------------------------
// edge kernel v5 = R4 structure + in-place LDS + natural VGPR:
// 32 sorted edges/block, 256 thr (4 waves col-split), LDS ~22KB.
// attr staged coalesced into LDS; bufA reused xsum->act1->act2 in place.
// ---------------------------------------------------------------------------
__global__ __launch_bounds__(256) void edge_kernel(
    const u16* __restrict__ Xb, const float* __restrict__ pos,
    const int* __restrict__ eidx, const float* __restrict__ eattr,
    const int* __restrict__ eorder,
    const u16* __restrict__ e1pt, const float* __restrict__ eb1,
    const u16* __restrict__ e2t, const float* __restrict__ eb2,
    const u16* __restrict__ c1t, const float* __restrict__ cb1,
    const float* __restrict__ cW2,
    float* __restrict__ agg_node, float* __restrict__ agg_coord)
{
    __shared__ u16 attr[EB * 64];     // 4 KB, swizzled rows (stride 128B)
    __shared__ u16 bufA[EB * 256];    // 16 KB, xsum -> act1 -> act2 in place
    __shared__ int ri_s[EB], ci_s[EB], es_s[EB];
    __shared__ float rad_s[EB], dif_s[EB][3];
    __shared__ float red[EB * 4];

    const int j = threadIdx.x, w = j >> 6, lane = j & 63;
    const int ml = lane & 15, g = lane >> 4;
    const int n0 = w * 64;            // this wave's col group
    const f32x4 z = {0.f, 0.f, 0.f, 0.f};

    // bijective XCD-chunked swizzle: consecutive sorted-edge blocks share L2
    const int nwg = gridDim.x;
    const int qq = nwg >> 3, r8 = nwg & 7;
    const int xcd = blockIdx.x & 7, sub = blockIdx.x >> 3;
    const int wg = (xcd < r8 ? xcd * (qq + 1) : r8 * (qq + 1) + (xcd - r8) * qq) + sub;
    const int e0 = wg * EB;

    if (j < EB) {
        int e = eorder[e0 + j];
        es_s[j] = e;
        int r = eidx[e], c = eidx[E_EDGES + e];
        ri_s[j] = r; ci_s[j] = c;
        float dx = pos[r * 3 + 0] - pos[c * 3 + 0];
        float dy = pos[r * 3 + 1] - pos[c * 3 + 1];
        float dz = pos[r * 3 + 2] - pos[c * 3 + 2];
        dif_s[j][0] = dx; dif_s[j][1] = dy; dif_s[j][2] = dz;
        rad_s[j] = sqrtf(dx * dx + dy * dy + dz * dz) + 1e-8f;
    }
    __syncthreads();

    // ---- cooperative gather: bufA[e][:] = Xr[ri[e]] + Xc[ci[e]] (bf16)
#pragma unroll
    for (int t = 0; t < 4; ++t) {
        int li = t * 256 + j;           // (edge, 16B-chunk)
        int e = li >> 5, c = li & 31;
        const u16x8 xr = *(const u16x8*)&Xb[(size_t)ri_s[e] * 768 + c * 8];
        const u16x8 xc = *(const u16x8*)&Xb[(size_t)ci_s[e] * 768 + 256 + c * 8];
        u32x4 o;
#pragma unroll
        for (int k = 0; k < 4; ++k)
            o[k] = cvtpk(bf2f(xr[2 * k]) + bf2f(xc[2 * k]),
                         bf2f(xr[2 * k + 1]) + bf2f(xc[2 * k + 1]));
        *(u32x4*)((char*)bufA + ((e * 512 + c * 16) ^ ((e & 7) << 4))) = o;
    }
    // ---- stage edge_attr (+radial in col 51), coalesced, once per block
    for (int li = j; li < EB * 64; li += 256) {
        int row = li >> 6, k = li & 63;
        float v = (k < 51) ? eattr[(size_t)es_s[row] * 51 + k] : (k == 51 ? rad_s[row] : 0.f);
        int byte = (row * 128 + k * 2) ^ ((row & 7) << 4);
        attr[byte >> 1] = f2bf(v);
    }
    __syncthreads();

    f32x4 acc[2][4];

    // ---- stage 1: attr/radial MFMA (K=64) + bias + xsum (in place), silu
#pragma unroll
    for (int mt = 0; mt < 2; ++mt)
#pragma unroll
        for (int nt = 0; nt < 4; ++nt) acc[mt][nt] = z;
#pragma unroll
    for (int kc = 0; kc < 2; ++kc) {
        bf16x8 a0 = *(const bf16x8*)((const char*)attr + ((ml * 128 + (kc * 32 + g * 8) * 2) ^ ((ml & 7) << 4)));
        bf16x8 a1 = *(const bf16x8*)((const char*)attr + (((16 + ml) * 128 + (kc * 32 + g * 8) * 2) ^ ((ml & 7) << 4)));
#pragma unroll
        for (int nt = 0; nt < 4; ++nt) {
            bf16x8 b = *(const bf16x8*)&e1pt[(size_t)(n0 + nt * 16 + ml) * 64 + kc * 32 + g * 8];
            acc[0][nt] = mfma16(a0, b, acc[0][nt]);
            acc[1][nt] = mfma16(a1, b, acc[1][nt]);
        }
    }
#pragma unroll
    for (int nt = 0; nt < 4; ++nt) {
        int col = n0 + nt * 16 + ml;
        float b1 = eb1[col];
#pragma unroll
        for (int mt = 0; mt < 2; ++mt)
#pragma unroll
            for (int i = 0; i < 4; ++i) {
                int row = mt * 16 + g * 4 + i;
                int off = actb(row, col) >> 1;
                float v = acc[mt][nt][i] + b1 + bf2f(bufA[off]);
                bufA[off] = f2bf(silu_f(v));        // same-thread in-place
            }
    }
    __syncthreads();

    // ---- stage 2 MFMA: e = act1 @ eW2 (K=256)
#pragma unroll
    for (int mt = 0; mt < 2; ++mt)
#pragma unroll
        for (int nt = 0; nt < 4; ++nt) acc[mt][nt] = z;
#pragma unroll
    for (int kc = 0; kc < 8; ++kc) {
        bf16x8 a0 = *(const bf16x8*)((const char*)bufA + actb(ml, kc * 32 + g * 8));
        bf16x8 a1 = *(const bf16x8*)((const char*)bufA + actb(16 + ml, kc * 32 + g * 8));
#pragma unroll
        for (int nt = 0; nt < 4; ++nt) {
            bf16x8 b = *(const bf16x8*)&e2t[(size_t)(n0 + nt * 16 + ml) * 256 + kc * 32 + g * 8];
            acc[0][nt] = mfma16(a0, b, acc[0][nt]);
            acc[1][nt] = mfma16(a1, b, acc[1][nt]);
        }
    }
    __syncthreads();   // all act1 reads complete before overwrite
#pragma unroll
    for (int nt = 0; nt < 4; ++nt) {
        int col = n0 + nt * 16 + ml;
        float b2 = eb2[col];
#pragma unroll
        for (int mt = 0; mt < 2; ++mt)
#pragma unroll
            for (int i = 0; i < 4; ++i) {
                int row = mt * 16 + g * 4 + i;
                bufA[actb(row, col) >> 1] = f2bf(silu_f(acc[mt][nt][i] + b2));
            }
    }
    __syncthreads();

    // ---- stage 3 MFMA: c = act2 @ cW1 (K=256)
#pragma unroll
    for (int mt = 0; mt < 2; ++mt)
#pragma unroll
        for (int nt = 0; nt < 4; ++nt) acc[mt][nt] = z;
#pragma unroll
    for (int kc = 0; kc < 8; ++kc) {
        bf16x8 a0 = *(const bf16x8*)((const char*)bufA + actb(ml, kc * 32 + g * 8));
        bf16x8 a1 = *(const bf16x8*)((const char*)bufA + actb(16 + ml, kc * 32 + g * 8));
#pragma unroll
        for (int nt = 0; nt < 4; ++nt) {
            bf16x8 b = *(const bf16x8*)&c1t[(size_t)(n0 + nt * 16 + ml) * 256 + kc * 32 + g * 8];
            acc[0][nt] = mfma16(a0, b, acc[0][nt]);
            acc[1][nt] = mfma16(a1, b, acc[1][nt]);
        }
    }

    // ---- run-length agg_node: thread owns one col; rows sorted -> one
    // atomic per distinct destination row (overlaps stage-3 epilogue).
    {
        int cur = ri_s[0];
        float s = bf2f(bufA[actb(0, j) >> 1]);
        for (int m = 1; m < EB; ++m) {
            int r = ri_s[m];
            float v = bf2f(bufA[actb(m, j) >> 1]);
            if (r != cur) {
                atomicAdd(&agg_node[(size_t)cur * 256 + j], s);
                s = 0.f; cur = r;
            }
            s += v;
        }
        atomicAdd(&agg_node[(size_t)cur * 256 + j], s);
    }

    // ---- stage 3 epilogue: u = clip((silu(c + cb1)) . cW2)
    float p[2][4] = {{0.f, 0.f, 0.f, 0.f}, {0.f, 0.f, 0.f, 0.f}};
#pragma unroll
    for (int nt = 0; nt < 4; ++nt) {
        int col = n0 + nt * 16 + ml;
        float b3 = cb1[col];
        float w2 = cW2[col];
#pragma unroll
        for (int mt = 0; mt < 2; ++mt)
#pragma unroll
            for (int i = 0; i < 4; ++i)
                p[mt][i] += silu_f(acc[mt][nt][i] + b3) * w2;
    }
#pragma unroll
    for (int mt = 0; mt < 2; ++mt)
#pragma unroll
        for (int i = 0; i < 4; ++i) {
            float v = p[mt][i];
            v += __shfl_xor(v, 1);
            v += __shfl_xor(v, 2);
            v += __shfl_xor(v, 4);
            v += __shfl_xor(v, 8);
            p[mt][i] = v;
        }
    if (ml == 0) {
#pragma unroll
        for (int mt = 0; mt < 2; ++mt)
#pragma unroll
            for (int i = 0; i < 4; ++i)
                red[(mt * 16 + g * 4 + i) * 4 + w] = p[mt][i];
    }
    __syncthreads();
    if (j < EB) {
        float u = red[j * 4 + 0] + red[j * 4 + 1] + red[j * 4 + 2] + red[j * 4 + 3];
        u = fminf(fmaxf(u, -1.f), 1.f);
        int rr = ri_s[j];
        atomicAdd(&agg_coord[(size_t)rr * 3 + 0], u * dif_s[j][0]);
        atomicAdd(&agg_coord[(size_t)rr * 3 + 1], u * dif_s[j][1]);
        atomicAdd(&agg_coord[(size_t)rr * 3 + 2], u * dif_s[j][2]);
    }
}

// ---------------------------------------------------------------------------
// node kernel: h_new = silu([h,agg] @ nW1 + nb1) @ nW2 + nb2 ; pos update
// ---------------------------------------------------------------------------
__global__ __launch_bounds__(256) void node_kernel(
    const u16* __restrict__ Xb, const float* __restrict__ agg_node,
    const float* __restrict__ agg_coord, const float* __restrict__ pos,
    const u16* __restrict__ n1t, const float* __restrict__ nb1,
    const u16* __restrict__ n2t, const float* __restrict__ nb2,
    float* __restrict__ out)
{
    __shared__ u16 act1[32 * 256];
    __shared__ u16 act2[32 * 256];
    const int n0b = blockIdx.x * 32;
    const int j = threadIdx.x, wv = j >> 6, lane = j & 63;
    const int ml = lane & 15, g = lane >> 4;
    const int n0 = wv * 64;
    const f32x4 z = {0.f, 0.f, 0.f, 0.f};

    for (int li = j; li < 32 * 256; li += 256) {
        int r = li >> 8, c = li & 255;
        act1[actb(r, c) >> 1] = f2bf(agg_node[(size_t)(n0b + r) * 256 + c]);
    }
    __syncthreads();

    f32x4 acc[2][4];
#pragma unroll
    for (int mt = 0; mt < 2; ++mt)
#pragma unroll
        for (int nt = 0; nt < 4; ++nt) acc[mt][nt] = z;
    for (int kc = 0; kc < 8; ++kc) {
        bf16x8 a0 = *(const bf16x8*)((const char*)act1 + actb(ml, kc * 32 + g * 8));
        bf16x8 a1 = *(const bf16x8*)((const char*)act1 + actb(16 + ml, kc * 32 + g * 8));
#pragma unroll
        for (int nt = 0; nt < 4; ++nt) {
            bf16x8 b = *(const bf16x8*)&n1t[(size_t)(n0 + nt * 16 + ml) * 256 + kc * 32 + g * 8];
            acc[0][nt] = mfma16(a0, b, acc[0][nt]);
            acc[1][nt] = mfma16(a1, b, acc[1][nt]);
        }
    }
#pragma unroll
    for (int mt = 0; mt < 2; ++mt)
#pragma unroll
        for (int nt = 0; nt < 4; ++nt) {
            int col = n0 + nt * 16 + ml;
            float b1 = nb1[col];
#pragma unroll
            for (int i = 0; i < 4; ++i) {
                int m = mt * 16 + g * 4 + i;
                float v = acc[mt][nt][i] + b1 + bf2f(Xb[(size_t)(n0b + m) * 768 + 512 + col]);
                act2[actb(m, col) >> 1] = f2bf(silu_f(v));
            }
        }
    __syncthreads();
#pragma unroll
    for (int mt = 0; mt < 2; ++mt)
#pragma unroll
        for (int nt = 0; nt < 4; ++nt) acc[mt][nt] = z;
    for (int kc = 0; kc < 8; ++kc) {
        bf16x8 a0 = *(const bf16x8*)((const char*)act2 + actb(ml, kc * 32 + g * 8));
        bf16x8 a1 = *(const bf16x8*)((const char*)act2 + actb(16 + ml, kc * 32 + g * 8));
#pragma unroll
        for (int nt = 0; nt < 4; ++nt) {
            bf16x8 b = *(const bf16x8*)&n2t[(size_t)(n0 + nt * 16 + ml) * 256 + kc * 32 + g * 8];
            acc[0][nt] = mfma16(a0, b, acc[0][nt]);
            acc[1][nt] = mfma16(a1, b, acc[1][nt]);
        }
    }
#pragma unroll
    for (int mt = 0; mt < 2; ++mt)
#pragma unroll
        for (int nt = 0; nt < 4; ++nt) {
            int col = n0 + nt * 16 + ml;
            float b2 = nb2[col];
#pragma unroll
            for (int i = 0; i < 4; ++i) {
                int row = n0b + mt * 16 + g * 4 + i;
                if (row < N_NODES)
                    out[(size_t)row * 256 + col] = acc[mt][nt][i] + b2;
            }
        }
    if (j < 96) {
        int idx = n0b * 3 + j;
        if (idx < N_NODES * 3)
            out[(size_t)N_NODES * 256 + idx] = pos[idx] + agg_coord[idx];
    }
}

// ---------------------------------------------------------------------------
extern "C" void kernel_launch(void* const* d_in, const int* in_sizes, int n_in,
                              void* d_out, int out_size, void* d_ws, size_t ws_size,
                              hipStream_t stream)
{
    (void)in_sizes; (void)n_in; (void)out_size; (void)ws_size;
    const float* h     = (const float*)d_in[0];
    const int*   eidx  = (const int*)d_in[1];
    const float* eattr = (const float*)d_in[2];
    const float* pos   = (const float*)d_in[3];
    const float* eW1   = (const float*)d_in[4];
    const float* eb1   = (const float*)d_in[5];
    const float* eW2   = (const float*)d_in[6];
    const float* eb2   = (const float*)d_in[7];
    const float* cW1   = (const float*)d_in[8];
    const float* cb1   = (const float*)d_in[9];
    const float* cW2   = (const float*)d_in[10];
    const float* nW1   = (const float*)d_in[11];
    const float* nb1   = (const float*)d_in[12];
    const float* nW2   = (const float*)d_in[13];
    const float* nb2   = (const float*)d_in[14];
    float* out = (float*)d_out;

    u16* Xb   = (u16*)d_ws;                                  // N_PAD*768 bf16
    u16* hb   = Xb + (size_t)N_PAD * 768;                    // N_PAD*512
    u16* Wt3  = hb + (size_t)N_PAD * 512;                    // 3*256*512
    u16* e1pt = Wt3 + 3 * 256 * 512;                         // 256*64
    u16* e2t  = e1pt + 256 * 64;                             // 256*256
    u16* c1t  = e2t + 256 * 256;
    u16* n1t  = c1t + 256 * 256;
    u16* n2t  = n1t + 256 * 256;
    float* agg_node  = (float*)(n2t + 256 * 256);            // N_PAD*256 f32
    float* agg_coord = agg_node + (size_t)N_PAD * 256;       // N_PAD*3  f32
    int* hist   = (int*)(agg_coord + (size_t)N_PAD * 3);     // N_PAD
    int* cnt    = hist + N_PAD;                              // N_PAD
    int* rowptr = cnt + N_PAD;                               // N_PAD+1
    int* eorder = rowptr + N_PAD + 1;                        // E

    hipMemsetAsync(agg_node, 0, (size_t)N_PAD * 259 * sizeof(float), stream);
    hipMemsetAsync(hist, 0, (size_t)2 * N_PAD * sizeof(int), stream);

    prep_weights<<<dim3(512, 8), 256, 0, stream>>>(eW1, eW2, cW1, nW1, nW2,
                                                   Wt3, e1pt, e2t, c1t, n1t, n2t);
    conv_h<<<(N_PAD * 512 / 8) / 256, 256, 0, stream>>>(h, hb);

    hist_kernel<<<(E_EDGES + 255) / 256, 256, 0, stream>>>(eidx, hist);
    scan_kernel<<<1, 256, 0, stream>>>(hist, rowptr);
    scatter_kernel<<<(E_EDGES + 255) / 256, 256, 0, stream>>>(eidx, rowptr, cnt, eorder);

    precompute_X<<<dim3(N_PAD / 32, 3), 256, 0, stream>>>(hb, Wt3, Xb);

    edge_kernel<<<E_EDGES / EB, 256, 0, stream>>>(
        Xb, pos, eidx, eattr, eorder, e1pt, eb1, e2t, eb2, c1t, cb1, cW2,
        agg_node, agg_coord);

    node_kernel<<<N_PAD / 32, 256, 0, stream>>>(
        Xb, agg_node, agg_coord, pos, n1t, nb1, n2t, nb2, out);
}